// Round 7
// baseline (546.277 us; speedup 1.0000x reference)
//
#include <hip/hip_runtime.h>
#include <math.h>

#define N_NODES 30000
#define N_EDGES 240000
#define DMODEL 256
#define NETYPES 8
#define NGRAPHS 64
#define NLAYERS 3

typedef __attribute__((ext_vector_type(8))) short short8;
typedef __attribute__((ext_vector_type(8))) unsigned short ushort8;
typedef __attribute__((ext_vector_type(4))) float f32x4;

// ---- bf16 split helpers (round-to-nearest-even) ----
__device__ __forceinline__ unsigned short f2bf(float f) {
  union { float f; unsigned u; } v; v.f = f;
  unsigned r = v.u + 0x7FFF + ((v.u >> 16) & 1);
  return (unsigned short)(r >> 16);
}
__device__ __forceinline__ float bf2f(unsigned short h) {
  union { unsigned u; float f; } v; v.u = ((unsigned)h) << 16;
  return v.f;
}

__device__ __forceinline__ void async_g2l(const unsigned short* g, unsigned short* l) {
  __builtin_amdgcn_global_load_lds(
      (const __attribute__((address_space(1))) void*)g,
      (__attribute__((address_space(3))) void*)l, 16, 0, 0);
}

// 16-lane (intra-head) sum via DPP.
__device__ __forceinline__ float dpp_red_add(float x) {
  int v = __float_as_int(x);
  int t;
  t = __builtin_amdgcn_update_dpp(0, v, 0xB1, 0xF, 0xF, true);   // quad_perm [1,0,3,2]
  v = __float_as_int(__int_as_float(v) + __int_as_float(t));
  t = __builtin_amdgcn_update_dpp(0, v, 0x4E, 0xF, 0xF, true);   // quad_perm [2,3,0,1]
  v = __float_as_int(__int_as_float(v) + __int_as_float(t));
  t = __builtin_amdgcn_update_dpp(0, v, 0x141, 0xF, 0xF, true);  // row_half_mirror (^7)
  v = __float_as_int(__int_as_float(v) + __int_as_float(t));
  t = __builtin_amdgcn_update_dpp(0, v, 0x140, 0xF, 0xF, true);  // row_mirror (^15)
  v = __float_as_int(__int_as_float(v) + __int_as_float(t));
  return __int_as_float(v);
}

// ---------------- fused prologue: count_deg | cvt_x | cvt_w | cvt_b | zero gacc ----
#define PREP_CNT 938
#define PREP_CVTX 3750
#define PREP_CVTW 576
#define PREP_CVTB 9
#define PREP_GACC 64
#define B_CVTX (PREP_CNT)
#define B_CVTW (B_CVTX + PREP_CVTX)
#define B_CVTB (B_CVTW + PREP_CVTW)
#define B_GACC (B_CVTB + PREP_CVTB)
#define PREP_BLOCKS (B_GACC + PREP_GACC)

__global__ __launch_bounds__(256) void k_prep(
    const int* __restrict__ dst, int* __restrict__ deg,
    const float* __restrict__ x, unsigned short* __restrict__ xhi,
    unsigned short* __restrict__ xlo,
    const float* __restrict__ Wq, const float* __restrict__ Wk,
    const float* __restrict__ Wv, unsigned short* __restrict__ wthi,
    const float* __restrict__ bq, const float* __restrict__ bk,
    const float* __restrict__ bv, float* __restrict__ bcat,
    float* __restrict__ gacc) {
  __shared__ float tile[32][33];
  int bid = blockIdx.x, t = threadIdx.x;
  if (bid < PREP_CNT) {
    int e = bid * 256 + t;
    if (e < N_EDGES) atomicAdd(&deg[dst[e]], 1);
  } else if (bid < B_CVTW) {
    size_t i0 = ((size_t)(bid - B_CVTX) * 256 + t) * 8;
#pragma unroll
    for (int h = 0; h < 2; ++h) {
      float4 v4 = *(const float4*)(x + i0 + h * 4);
      ushort4 hv, lv;
      hv.x = f2bf(v4.x); lv.x = f2bf(v4.x - bf2f(hv.x));
      hv.y = f2bf(v4.y); lv.y = f2bf(v4.y - bf2f(hv.y));
      hv.z = f2bf(v4.z); lv.z = f2bf(v4.z - bf2f(hv.z));
      hv.w = f2bf(v4.w); lv.w = f2bf(v4.w - bf2f(hv.w));
      *(ushort4*)(xhi + i0 + h * 4) = hv;
      *(ushort4*)(xlo + i0 + h * 4) = lv;
    }
  } else if (bid < B_CVTB) {
    int rel = bid - B_CVTW;
    int k0 = (rel & 7) * 32;
    int n0g = ((rel >> 3) % 24) * 32;
    int l = rel / 192;
    int which = n0g >> 8;
    int col0 = n0g & 255;
    const float* W = (which == 0) ? Wq : ((which == 1) ? Wk : Wv);
    int c = t & 31, r = t >> 5;
#pragma unroll
    for (int rr = 0; rr < 4; ++rr) {
      int kk = r + rr * 8;
      tile[kk][c] = W[(size_t)l * 65536 + (size_t)(k0 + kk) * 256 + col0 + c];
    }
    __syncthreads();
    int kk = t & 31, nn0 = t >> 5;
#pragma unroll
    for (int rr = 0; rr < 4; ++rr) {
      int nn = nn0 + rr * 8;
      wthi[((size_t)l * 768 + n0g + nn) * 256 + k0 + kk] = f2bf(tile[kk][nn]);
    }
  } else if (bid < B_GACC) {
    int idx = (bid - B_CVTB) * 256 + t;
    if (idx < NLAYERS * 768) {
      int n = idx % 768, l = idx / 768;
      int which = n >> 8, col = n & 255;
      const float* b = (which == 0) ? bq : ((which == 1) ? bk : bv);
      bcat[idx] = b[l * 256 + col];
    }
  } else {
    int idx = (bid - B_GACC) * 256 + t;
    gacc[idx] = 0.f;
  }
}

// ---------------- scan + histogram (single deg pass); bucket cursors to global ----
__global__ __launch_bounds__(1024) void k_scan_sort(
    const int* __restrict__ deg, int* __restrict__ rowstart,
    int* __restrict__ cursor, int* __restrict__ bcur_g) {
  const int C = 30;
  __shared__ int hist[256];
  int tid = threadIdx.x;
  if (tid < 256) hist[tid] = 0;
  __syncthreads();
  int base = tid * C;
  int vals[C];
  int sum = 0;
#pragma unroll
  for (int j = 0; j < C; ++j) {
    int idx = base + j;
    int v = (idx < N_NODES) ? deg[idx] : 0;
    if (idx < N_NODES) {
      int d = v > 255 ? 255 : v;
      atomicAdd(&hist[d], 1);      // reuse the already-loaded value
    }
    vals[j] = sum;
    sum += v;
  }
  int lane = tid & 63, wv = tid >> 6;
  int s = sum;
#pragma unroll
  for (int off = 1; off < 64; off <<= 1) {
    int t2 = __shfl_up(s, off);
    if (lane >= off) s += t2;
  }
  __shared__ int wsum[16];
  if (lane == 63) wsum[wv] = s;
  __syncthreads();
  if (tid == 0) {
    int a = 0;
#pragma unroll
    for (int i = 0; i < 16; ++i) { int t2 = wsum[i]; wsum[i] = a; a += t2; }
    rowstart[N_NODES] = a;
    // descending exclusive scan of hist -> bucket starts (256 LDS ops, cheap)
    int b = 0;
    for (int d = 255; d >= 0; --d) { int h = hist[d]; hist[d] = b; b += h; }
  }
  __syncthreads();
  int texcl = wsum[wv] + (s - sum);
#pragma unroll
  for (int j = 0; j < C; ++j) {
    int idx = base + j;
    if (idx < N_NODES) {
      int p = texcl + vals[j];
      rowstart[idx] = p;
      cursor[idx]   = p;
    }
  }
  if (tid < 256) bcur_g[tid] = hist[tid];
}

// ---------------- edge scatter + parallel perm placement ----------------
#define SCAT_EB ((N_EDGES + 255) / 256)   // 938
#define SCAT_NB ((N_NODES + 255) / 256)   // 118
__global__ void k_scatter(const int* __restrict__ src, const int* __restrict__ dst,
                          const int* __restrict__ etype, int* __restrict__ cursor,
                          int* __restrict__ packed, const int* __restrict__ deg,
                          int* __restrict__ bcur_g, int* __restrict__ perm) {
  int bid = blockIdx.x;
  if (bid < SCAT_EB) {
    int e = bid * 256 + threadIdx.x;
    if (e < N_EDGES) {
      int p = atomicAdd(&cursor[dst[e]], 1);
      packed[p] = src[e] * NETYPES + etype[e];
    }
  } else {
    int i = (bid - SCAT_EB) * 256 + threadIdx.x;
    if (i < N_NODES) {
      int d = deg[i]; if (d > 255) d = 255;
      int pos = atomicAdd(&bcur_g[d], 1);
      perm[pos] = i;
    }
  }
}

// ---------------- split-bf16 MFMA GEMM, 2-term (Ahi*Bhi + Alo*Bhi) ----------
__global__ __launch_bounds__(256, 5) void k_gemm_mfma(
    const unsigned short* __restrict__ Ahi, const unsigned short* __restrict__ Alo,
    const unsigned short* __restrict__ Bhi,
    const float* __restrict__ bcat, float* __restrict__ qbuf,
    unsigned short* __restrict__ kv) {
  __shared__ unsigned short smem[2 * 8192];

  int tid = threadIdx.x;
  int lane = tid & 63, wave = tid >> 6;
  int bx = blockIdx.x;
  int xcd = bx & 7, slot = bx >> 3;
  int rt = xcd + (slot / 6) * 8;
  if (rt >= 469) return;
  int row0 = rt * 64;
  int n0 = (slot % 6) * 128;
  int wm = (wave >> 1) * 32, wn = (wave & 1) * 64;
  int quad = lane >> 4, l16 = lane & 15;
  int lrow = lane >> 2;
  int chSw = (lane & 3) ^ ((lane >> 3) & 3);
  int rdSw = (quad ^ ((l16 >> 1) & 3)) * 8;

  f32x4 acc[2][4];
#pragma unroll
  for (int i = 0; i < 2; ++i)
#pragma unroll
    for (int j = 0; j < 4; ++j) acc[i][j] = (f32x4)(0.f);

  auto STAGE = [&](int k0, int b) {
    unsigned short* s = smem + b * 8192;
    int garA = row0 + wave * 16 + lrow; if (garA >= N_NODES) garA = N_NODES - 1;
    size_t acol = (size_t)garA * 256 + k0 + chSw * 8;
    async_g2l(Ahi + acol, s + wave * 512);
    async_g2l(Alo + acol, s + 2048 + wave * 512);
#pragma unroll
    for (int r = 0; r < 2; ++r) {
      int brow = r * 64 + wave * 16 + lrow;
      size_t boff = (size_t)(n0 + brow) * 256 + k0 + chSw * 8;
      async_g2l(Bhi + boff, s + 4096 + r * 2048 + wave * 512);
    }
  };

  STAGE(0, 0);
#pragma unroll
  for (int k = 0; k < 8; ++k) {
    int cur = k & 1;
    if (k < 7) {
      STAGE((k + 1) * 32, cur ^ 1);
      asm volatile("s_waitcnt vmcnt(4)" ::: "memory");
    } else {
      asm volatile("s_waitcnt vmcnt(0)" ::: "memory");
    }
    __builtin_amdgcn_s_barrier();

    const unsigned short* sAhi = smem + cur * 8192;
    const unsigned short* sAlo = sAhi + 2048;
    const unsigned short* sB   = sAhi + 4096;
    short8 ah[2], al[2], bh[4];
#pragma unroll
    for (int i = 0; i < 2; ++i) {
      int off = (wm + i * 16 + l16) * 32 + rdSw;
      ah[i] = *(const short8*)(sAhi + off);
      al[i] = *(const short8*)(sAlo + off);
    }
#pragma unroll
    for (int j = 0; j < 4; ++j) {
      int off = (wn + j * 16 + l16) * 32 + rdSw;
      bh[j] = *(const short8*)(sB + off);
    }
#pragma unroll
    for (int i = 0; i < 2; ++i)
#pragma unroll
      for (int j = 0; j < 4; ++j) {
        acc[i][j] = __builtin_amdgcn_mfma_f32_16x16x32_bf16(ah[i], bh[j], acc[i][j], 0, 0, 0);
        acc[i][j] = __builtin_amdgcn_mfma_f32_16x16x32_bf16(al[i], bh[j], acc[i][j], 0, 0, 0);
      }
    __builtin_amdgcn_s_barrier();
  }

  float bj[4];
#pragma unroll
  for (int j = 0; j < 4; ++j) bj[j] = bcat[n0 + wn + j * 16 + l16];
  bool isq = (n0 < 256);
  int cb = n0 - 256;
  int isV = cb >> 8;
  int cc0 = (cb & 255) + wn + l16;
#pragma unroll
  for (int i = 0; i < 2; ++i) {
    int rowb = row0 + wm + i * 16 + quad * 4;
#pragma unroll
    for (int r = 0; r < 4; ++r) {
      int grow = rowb + r;
      if (grow < N_NODES) {
        if (isq) {
          float* cp = qbuf + (size_t)grow * 256 + n0 + wn + l16;
#pragma unroll
          for (int j = 0; j < 4; ++j) cp[j * 16] = acc[i][j][r] + bj[j];
        } else {
          unsigned short* rowp = kv + (size_t)grow * 512 + isV * 4;
#pragma unroll
          for (int j = 0; j < 4; ++j) {
            int c = cc0 + j * 16;
            rowp[((c >> 2) << 3) + (c & 3)] = f2bf(acc[i][j][r] + bj[j]);
          }
        }
      }
    }
  }
}

// ---------------- per-dst-node edge attention (degree-sorted via perm) ----------
__global__ __launch_bounds__(256) void k_attn(
    const float* __restrict__ qbuf, const unsigned short* __restrict__ kv,
    const int* __restrict__ rowstart, const int* __restrict__ packed,
    const int* __restrict__ perm, const float* __restrict__ Eemb_l,
    unsigned short* __restrict__ xhi, unsigned short* __restrict__ xlo) {
  __shared__ float ete_s[NETYPES * 256];
  int t = threadIdx.x;
#pragma unroll
  for (int i = 0; i < NETYPES; ++i) ete_s[i * 256 + t] = Eemb_l[i * 256 + t];
  __syncthreads();
  int lane = t & 63;
  int n = perm[blockIdx.x * 4 + (t >> 6)];
  float4 q4 = ((const float4*)(qbuf + (size_t)n * 256))[lane];
  int rs = rowstart[n], re = rowstart[n + 1];
  float l1 = 0.f, ax1 = 0.f, ay1 = 0.f, az1 = 0.f, aw1 = 0.f;
  float l2 = 0.f, ax2 = 0.f, ay2 = 0.f, az2 = 0.f, aw2 = 0.f;
  int i = rs;
  for (; i + 2 <= re; i += 2) {
    int pkA = packed[i], pkB = packed[i + 1];
    ushort8 cA = ((const ushort8*)(kv + (size_t)(pkA >> 3) * 512))[lane];
    ushort8 cB = ((const ushort8*)(kv + (size_t)(pkB >> 3) * 512))[lane];
    float4 eA = ((const float4*)(ete_s + (pkA & 7) * 256))[lane];
    float4 eB = ((const float4*)(ete_s + (pkB & 7) * 256))[lane];
    float pA = (bf2f(cA[0]) + eA.x) * q4.x + (bf2f(cA[1]) + eA.y) * q4.y +
               (bf2f(cA[2]) + eA.z) * q4.z + (bf2f(cA[3]) + eA.w) * q4.w;
    float pB = (bf2f(cB[0]) + eB.x) * q4.x + (bf2f(cB[1]) + eB.y) * q4.y +
               (bf2f(cB[2]) + eB.z) * q4.z + (bf2f(cB[3]) + eB.w) * q4.w;
    pA = dpp_red_add(pA);
    pB = dpp_red_add(pB);
    float e1 = __expf(pA * 0.125f);
    float e2 = __expf(pB * 0.125f);
    l1 += e1; l2 += e2;
    ax1 = fmaf(e1, bf2f(cA[4]) + eA.x, ax1);
    ay1 = fmaf(e1, bf2f(cA[5]) + eA.y, ay1);
    az1 = fmaf(e1, bf2f(cA[6]) + eA.z, az1);
    aw1 = fmaf(e1, bf2f(cA[7]) + eA.w, aw1);
    ax2 = fmaf(e2, bf2f(cB[4]) + eB.x, ax2);
    ay2 = fmaf(e2, bf2f(cB[5]) + eB.y, ay2);
    az2 = fmaf(e2, bf2f(cB[6]) + eB.z, az2);
    aw2 = fmaf(e2, bf2f(cB[7]) + eB.w, aw2);
  }
  if (i < re) {
    int pk = packed[i];
    ushort8 c = ((const ushort8*)(kv + (size_t)(pk >> 3) * 512))[lane];
    float4 e4 = ((const float4*)(ete_s + (pk & 7) * 256))[lane];
    float p = (bf2f(c[0]) + e4.x) * q4.x + (bf2f(c[1]) + e4.y) * q4.y +
              (bf2f(c[2]) + e4.z) * q4.z + (bf2f(c[3]) + e4.w) * q4.w;
    p = dpp_red_add(p);
    float e1 = __expf(p * 0.125f);
    l1 += e1;
    ax1 = fmaf(e1, bf2f(c[4]) + e4.x, ax1);
    ay1 = fmaf(e1, bf2f(c[5]) + e4.y, ay1);
    az1 = fmaf(e1, bf2f(c[6]) + e4.z, az1);
    aw1 = fmaf(e1, bf2f(c[7]) + e4.w, aw1);
  }
  float l = l1 + l2;
  float inv = 1.f / (l + 1e-16f);
  float4 o;
  o.x = (ax1 + ax2) * inv; o.y = (ay1 + ay2) * inv;
  o.z = (az1 + az2) * inv; o.w = (aw1 + aw2) * inv;
  o.x = o.x > 0.f ? o.x : expm1f(o.x);
  o.y = o.y > 0.f ? o.y : expm1f(o.y);
  o.z = o.z > 0.f ? o.z : expm1f(o.z);
  o.w = o.w > 0.f ? o.w : expm1f(o.w);
  unsigned short h0 = f2bf(o.x), h1 = f2bf(o.y), h2 = f2bf(o.z), h3 = f2bf(o.w);
  ushort4 hv, lv;
  hv.x = h0; hv.y = h1; hv.z = h2; hv.w = h3;
  lv.x = f2bf(o.x - bf2f(h0)); lv.y = f2bf(o.y - bf2f(h1));
  lv.z = f2bf(o.z - bf2f(h2)); lv.w = f2bf(o.w - bf2f(h3));
  size_t base_o = (size_t)n * 256 + lane * 4;
  *(ushort4*)(xhi + base_o) = hv;
  *(ushort4*)(xlo + base_o) = lv;
}

// ---------------- parallel mean pool, stage 1 ----------------
__global__ __launch_bounds__(256) void k_pool_partial(
    const unsigned short* __restrict__ xhi, const unsigned short* __restrict__ xlo,
    const int* __restrict__ batch, float* __restrict__ gacc) {
  int t = threadIdx.x;
  int base = blockIdx.x * 128;
  int end = base + 128; if (end > N_NODES) end = N_NODES;
  __shared__ int bsh[128];
  if (t < 128 && base + t < N_NODES) bsh[t] = batch[base + t];
  __syncthreads();
  float acc = 0.f;
  int cur = bsh[0];
  for (int n = base; n < end; ++n) {
    int g = bsh[n - base];
    if (g != cur) {
      atomicAdd(&gacc[cur * 256 + t], acc);
      acc = 0.f; cur = g;
    }
    size_t idx = (size_t)n * 256 + t;
    acc += bf2f(xhi[idx]) + bf2f(xlo[idx]);
  }
  atomicAdd(&gacc[cur * 256 + t], acc);
}

// ---------------- GRU (h0=0) + FC ----------------
__device__ inline int lower_bound_dev(const int* a, int n, int val) {
  int lo = 0, hi = n;
  while (lo < hi) {
    int mid = (lo + hi) >> 1;
    if (a[mid] < val) lo = mid + 1; else hi = mid;
  }
  return lo;
}

__global__ __launch_bounds__(256) void k_gru_fc(
    const float* __restrict__ gacc, const int* __restrict__ batch,
    const float* __restrict__ W_ih, const float* __restrict__ b_ih,
    const float* __restrict__ b_hh, const float* __restrict__ W_fc,
    const float* __restrict__ b_fc, float* __restrict__ out) {
  __shared__ float gv[256];
  __shared__ float gates[192];
  __shared__ float h[64];
  int gr = blockIdx.x, t = threadIdx.x;
  int s0 = lower_bound_dev(batch, N_NODES, gr);
  int e0 = lower_bound_dev(batch, N_NODES, gr + 1);
  float c = (e0 > s0) ? (float)(e0 - s0) : 1.f;
  gv[t] = gacc[gr * 256 + t] / c;
  __syncthreads();
  if (t < 192) {
    const float* wr = W_ih + t * 256;
    float s = b_ih[t];
    for (int k = 0; k < 256; ++k) s = fmaf(gv[k], wr[k], s);
    gates[t] = s;
  }
  __syncthreads();
  if (t < 64) {
    float r  = 1.f / (1.f + expf(-(gates[t] + b_hh[t])));
    float z  = 1.f / (1.f + expf(-(gates[64 + t] + b_hh[64 + t])));
    float nn = tanhf(gates[128 + t] + r * b_hh[128 + t]);
    h[t] = (1.f - z) * nn;
  }
  __syncthreads();
  if (t < 2) {
    const float* wr = W_fc + t * 64;
    float s = b_fc[t];
    for (int k = 0; k < 64; ++k) s = fmaf(h[k], wr[k], s);
    out[gr * 2 + t] = s;
  }
}

extern "C" void kernel_launch(void* const* d_in, const int* in_sizes, int n_in,
                              void* d_out, int out_size, void* d_ws, size_t ws_size,
                              hipStream_t stream) {
  const float* x     = (const float*)d_in[0];
  const int* edge_index = (const int*)d_in[1];
  const int* batch   = (const int*)d_in[2];
  const int* etype   = (const int*)d_in[3];
  const float* Wq    = (const float*)d_in[4];
  const float* bq    = (const float*)d_in[5];
  const float* Wk    = (const float*)d_in[6];
  const float* bk    = (const float*)d_in[7];
  const float* Wv    = (const float*)d_in[8];
  const float* bv    = (const float*)d_in[9];
  const float* Eemb  = (const float*)d_in[10];
  const float* W_ih  = (const float*)d_in[11];
  const float* b_ih  = (const float*)d_in[12];
  const float* b_hh  = (const float*)d_in[14];
  const float* W_fc  = (const float*)d_in[15];
  const float* b_fc  = (const float*)d_in[16];
  float* out = (float*)d_out;

  const int* src = edge_index;
  const int* dst = edge_index + N_EDGES;

  float* qbuf  = (float*)d_ws;                             // N*256 f32
  float* gacc  = qbuf + (size_t)N_NODES * 256;             // 64*256
  float* bcat  = gacc + NGRAPHS * 256;                     // 3*768
  unsigned short* kv   = (unsigned short*)(bcat + NLAYERS * 768);  // N*512 bf16
  unsigned short* xhi  = kv + (size_t)N_NODES * 512;       // N*256
  unsigned short* xlo  = xhi + (size_t)N_NODES * 256;
  unsigned short* wthi = xlo + (size_t)N_NODES * 256;      // 3*768*256
  int* deg      = (int*)(wthi + (size_t)NLAYERS * 768 * 256);
  int* rowstart = deg + N_NODES;
  int* cursor   = rowstart + N_NODES + 1;
  int* packed   = cursor + N_NODES;
  int* perm     = packed + N_EDGES;
  int* bcur_g   = perm + N_NODES;

  hipMemsetAsync(deg, 0, N_NODES * sizeof(int), stream);
  k_prep<<<PREP_BLOCKS, 256, 0, stream>>>(dst, deg, x, xhi, xlo,
                                          Wq, Wk, Wv, wthi, bq, bk, bv, bcat, gacc);
  k_scan_sort<<<1, 1024, 0, stream>>>(deg, rowstart, cursor, bcur_g);
  k_scatter<<<SCAT_EB + SCAT_NB, 256, 0, stream>>>(src, dst, etype, cursor, packed,
                                                   deg, bcur_g, perm);

  for (int l = 0; l < NLAYERS; ++l) {
    k_gemm_mfma<<<59 * 8 * 6, 256, 0, stream>>>(
        xhi, xlo, wthi + (size_t)l * 768 * 256,
        bcat + l * 768, qbuf, kv);
    k_attn<<<N_NODES / 4, 256, 0, stream>>>(qbuf, kv, rowstart, packed, perm,
                                            Eemb + (size_t)l * NETYPES * 256, xhi, xlo);
  }
  k_pool_partial<<<(N_NODES + 127) / 128, 256, 0, stream>>>(xhi, xlo, batch, gacc);
  k_gru_fc<<<NGRAPHS, 256, 0, stream>>>(gacc, batch, W_ih, b_ih, b_hh, W_fc, b_fc, out);
}

// Round 8
// 456.723 us; speedup vs baseline: 1.1961x; 1.1961x over previous
//
#include <hip/hip_runtime.h>
#include <math.h>

#define N_NODES 30000
#define N_EDGES 240000
#define DMODEL 256
#define NETYPES 8
#define NGRAPHS 64
#define NLAYERS 3

typedef __attribute__((ext_vector_type(8))) short short8;
typedef __attribute__((ext_vector_type(8))) unsigned short ushort8;
typedef __attribute__((ext_vector_type(4))) float f32x4;

// ---- bf16 split helpers (round-to-nearest-even) ----
__device__ __forceinline__ unsigned short f2bf(float f) {
  union { float f; unsigned u; } v; v.f = f;
  unsigned r = v.u + 0x7FFF + ((v.u >> 16) & 1);
  return (unsigned short)(r >> 16);
}
__device__ __forceinline__ float bf2f(unsigned short h) {
  union { unsigned u; float f; } v; v.u = ((unsigned)h) << 16;
  return v.f;
}

__device__ __forceinline__ void async_g2l(const unsigned short* g, unsigned short* l) {
  __builtin_amdgcn_global_load_lds(
      (const __attribute__((address_space(1))) void*)g,
      (__attribute__((address_space(3))) void*)l, 16, 0, 0);
}

// 16-lane (intra-head) sum via DPP.
__device__ __forceinline__ float dpp_red_add(float x) {
  int v = __float_as_int(x);
  int t;
  t = __builtin_amdgcn_update_dpp(0, v, 0xB1, 0xF, 0xF, true);   // quad_perm [1,0,3,2]
  v = __float_as_int(__int_as_float(v) + __int_as_float(t));
  t = __builtin_amdgcn_update_dpp(0, v, 0x4E, 0xF, 0xF, true);   // quad_perm [2,3,0,1]
  v = __float_as_int(__int_as_float(v) + __int_as_float(t));
  t = __builtin_amdgcn_update_dpp(0, v, 0x141, 0xF, 0xF, true);  // row_half_mirror (^7)
  v = __float_as_int(__int_as_float(v) + __int_as_float(t));
  t = __builtin_amdgcn_update_dpp(0, v, 0x140, 0xF, 0xF, true);  // row_mirror (^15)
  v = __float_as_int(__int_as_float(v) + __int_as_float(t));
  return __int_as_float(v);
}

// ---------------- fused prologue: count_deg | cvt_x | cvt_w | cvt_b | zero gacc ----
#define PREP_CNT 938
#define PREP_CVTX 3750
#define PREP_CVTW 576
#define PREP_CVTB 9
#define PREP_GACC 64
#define B_CVTX (PREP_CNT)
#define B_CVTW (B_CVTX + PREP_CVTX)
#define B_CVTB (B_CVTW + PREP_CVTW)
#define B_GACC (B_CVTB + PREP_CVTB)
#define PREP_BLOCKS (B_GACC + PREP_GACC)

__global__ __launch_bounds__(256) void k_prep(
    const int* __restrict__ dst, int* __restrict__ deg,
    const float* __restrict__ x, unsigned short* __restrict__ xhi,
    unsigned short* __restrict__ xlo,
    const float* __restrict__ Wq, const float* __restrict__ Wk,
    const float* __restrict__ Wv, unsigned short* __restrict__ wthi,
    const float* __restrict__ bq, const float* __restrict__ bk,
    const float* __restrict__ bv, float* __restrict__ bcat,
    float* __restrict__ gacc) {
  __shared__ float tile[32][33];
  int bid = blockIdx.x, t = threadIdx.x;
  if (bid < PREP_CNT) {
    int e = bid * 256 + t;
    if (e < N_EDGES) atomicAdd(&deg[dst[e]], 1);
  } else if (bid < B_CVTW) {
    size_t i0 = ((size_t)(bid - B_CVTX) * 256 + t) * 8;
#pragma unroll
    for (int h = 0; h < 2; ++h) {
      float4 v4 = *(const float4*)(x + i0 + h * 4);
      ushort4 hv, lv;
      hv.x = f2bf(v4.x); lv.x = f2bf(v4.x - bf2f(hv.x));
      hv.y = f2bf(v4.y); lv.y = f2bf(v4.y - bf2f(hv.y));
      hv.z = f2bf(v4.z); lv.z = f2bf(v4.z - bf2f(hv.z));
      hv.w = f2bf(v4.w); lv.w = f2bf(v4.w - bf2f(hv.w));
      *(ushort4*)(xhi + i0 + h * 4) = hv;
      *(ushort4*)(xlo + i0 + h * 4) = lv;
    }
  } else if (bid < B_CVTB) {
    int rel = bid - B_CVTW;
    int k0 = (rel & 7) * 32;
    int n0g = ((rel >> 3) % 24) * 32;
    int l = rel / 192;
    int which = n0g >> 8;
    int col0 = n0g & 255;
    const float* W = (which == 0) ? Wq : ((which == 1) ? Wk : Wv);
    int c = t & 31, r = t >> 5;
#pragma unroll
    for (int rr = 0; rr < 4; ++rr) {
      int kk = r + rr * 8;
      tile[kk][c] = W[(size_t)l * 65536 + (size_t)(k0 + kk) * 256 + col0 + c];
    }
    __syncthreads();
    int kk = t & 31, nn0 = t >> 5;
#pragma unroll
    for (int rr = 0; rr < 4; ++rr) {
      int nn = nn0 + rr * 8;
      wthi[((size_t)l * 768 + n0g + nn) * 256 + k0 + kk] = f2bf(tile[kk][nn]);
    }
  } else if (bid < B_GACC) {
    int idx = (bid - B_CVTB) * 256 + t;
    if (idx < NLAYERS * 768) {
      int n = idx % 768, l = idx / 768;
      int which = n >> 8, col = n & 255;
      const float* b = (which == 0) ? bq : ((which == 1) ? bk : bv);
      bcat[idx] = b[l * 256 + col];
    }
  } else {
    int idx = (bid - B_GACC) * 256 + t;
    gacc[idx] = 0.f;
  }
}

// ---------------- scan + histogram (single deg pass); bucket cursors to global ----
__global__ __launch_bounds__(1024) void k_scan_sort(
    const int* __restrict__ deg, int* __restrict__ rowstart,
    int* __restrict__ cursor, int* __restrict__ bcur_g) {
  const int C = 30;
  __shared__ int hist[256];
  int tid = threadIdx.x;
  if (tid < 256) hist[tid] = 0;
  __syncthreads();
  int base = tid * C;
  int vals[C];
  int sum = 0;
#pragma unroll
  for (int j = 0; j < C; ++j) {
    int idx = base + j;
    int v = (idx < N_NODES) ? deg[idx] : 0;
    if (idx < N_NODES) {
      int d = v > 255 ? 255 : v;
      atomicAdd(&hist[d], 1);      // reuse the already-loaded value
    }
    vals[j] = sum;
    sum += v;
  }
  int lane = tid & 63, wv = tid >> 6;
  int s = sum;
#pragma unroll
  for (int off = 1; off < 64; off <<= 1) {
    int t2 = __shfl_up(s, off);
    if (lane >= off) s += t2;
  }
  __shared__ int wsum[16];
  if (lane == 63) wsum[wv] = s;
  __syncthreads();
  if (tid == 0) {
    int a = 0;
#pragma unroll
    for (int i = 0; i < 16; ++i) { int t2 = wsum[i]; wsum[i] = a; a += t2; }
    rowstart[N_NODES] = a;
    // descending exclusive scan of hist -> bucket starts
    int b = 0;
    for (int d = 255; d >= 0; --d) { int h = hist[d]; hist[d] = b; b += h; }
  }
  __syncthreads();
  int texcl = wsum[wv] + (s - sum);
#pragma unroll
  for (int j = 0; j < C; ++j) {
    int idx = base + j;
    if (idx < N_NODES) {
      int p = texcl + vals[j];
      rowstart[idx] = p;
      cursor[idx]   = p;
    }
  }
  if (tid < 256) bcur_g[tid] = hist[tid];
}

// ---------------- edge scatter + two-level perm placement ----------------
// Perm placement uses block-local LDS histogram + ONE global atomic per
// (block, non-empty bucket) — contention per address drops ~4200 -> <=118
// (round-7's flat per-node atomics on the d=8 bucket cost ~90us).
#define SCAT_EB ((N_EDGES + 255) / 256)   // 938
#define SCAT_NB ((N_NODES + 255) / 256)   // 118
__global__ __launch_bounds__(256) void k_scatter(
    const int* __restrict__ src, const int* __restrict__ dst,
    const int* __restrict__ etype, int* __restrict__ cursor,
    int* __restrict__ packed, const int* __restrict__ deg,
    int* __restrict__ bcur_g, int* __restrict__ perm) {
  int bid = blockIdx.x;
  int t = threadIdx.x;
  if (bid < SCAT_EB) {
    int e = bid * 256 + t;
    if (e < N_EDGES) {
      int p = atomicAdd(&cursor[dst[e]], 1);
      packed[p] = src[e] * NETYPES + etype[e];
    }
  } else {
    __shared__ int hist[256], lbase[256], lcur[256];
    hist[t] = 0;
    lcur[t] = 0;
    __syncthreads();
    int i = (bid - SCAT_EB) * 256 + t;
    int d = 0;
    bool valid = (i < N_NODES);
    if (valid) {
      d = deg[i]; if (d > 255) d = 255;
      atomicAdd(&hist[d], 1);
    }
    __syncthreads();
    int h = hist[t];
    if (h > 0) lbase[t] = atomicAdd(&bcur_g[t], h);
    __syncthreads();
    if (valid) {
      int r = atomicAdd(&lcur[d], 1);
      perm[lbase[d] + r] = i;
    }
  }
}

// ---------------- split-bf16 MFMA GEMM, 2-term (Ahi*Bhi + Alo*Bhi) ----------
__global__ __launch_bounds__(256, 5) void k_gemm_mfma(
    const unsigned short* __restrict__ Ahi, const unsigned short* __restrict__ Alo,
    const unsigned short* __restrict__ Bhi,
    const float* __restrict__ bcat, float* __restrict__ qbuf,
    unsigned short* __restrict__ kv) {
  __shared__ unsigned short smem[2 * 8192];

  int tid = threadIdx.x;
  int lane = tid & 63, wave = tid >> 6;
  int bx = blockIdx.x;
  int xcd = bx & 7, slot = bx >> 3;
  int rt = xcd + (slot / 6) * 8;
  if (rt >= 469) return;
  int row0 = rt * 64;
  int n0 = (slot % 6) * 128;
  int wm = (wave >> 1) * 32, wn = (wave & 1) * 64;
  int quad = lane >> 4, l16 = lane & 15;
  int lrow = lane >> 2;
  int chSw = (lane & 3) ^ ((lane >> 3) & 3);
  int rdSw = (quad ^ ((l16 >> 1) & 3)) * 8;

  f32x4 acc[2][4];
#pragma unroll
  for (int i = 0; i < 2; ++i)
#pragma unroll
    for (int j = 0; j < 4; ++j) acc[i][j] = (f32x4)(0.f);

  auto STAGE = [&](int k0, int b) {
    unsigned short* s = smem + b * 8192;
    int garA = row0 + wave * 16 + lrow; if (garA >= N_NODES) garA = N_NODES - 1;
    size_t acol = (size_t)garA * 256 + k0 + chSw * 8;
    async_g2l(Ahi + acol, s + wave * 512);
    async_g2l(Alo + acol, s + 2048 + wave * 512);
#pragma unroll
    for (int r = 0; r < 2; ++r) {
      int brow = r * 64 + wave * 16 + lrow;
      size_t boff = (size_t)(n0 + brow) * 256 + k0 + chSw * 8;
      async_g2l(Bhi + boff, s + 4096 + r * 2048 + wave * 512);
    }
  };

  STAGE(0, 0);
#pragma unroll
  for (int k = 0; k < 8; ++k) {
    int cur = k & 1;
    if (k < 7) {
      STAGE((k + 1) * 32, cur ^ 1);
      asm volatile("s_waitcnt vmcnt(4)" ::: "memory");
    } else {
      asm volatile("s_waitcnt vmcnt(0)" ::: "memory");
    }
    __builtin_amdgcn_s_barrier();

    const unsigned short* sAhi = smem + cur * 8192;
    const unsigned short* sAlo = sAhi + 2048;
    const unsigned short* sB   = sAhi + 4096;
    short8 ah[2], al[2], bh[4];
#pragma unroll
    for (int i = 0; i < 2; ++i) {
      int off = (wm + i * 16 + l16) * 32 + rdSw;
      ah[i] = *(const short8*)(sAhi + off);
      al[i] = *(const short8*)(sAlo + off);
    }
#pragma unroll
    for (int j = 0; j < 4; ++j) {
      int off = (wn + j * 16 + l16) * 32 + rdSw;
      bh[j] = *(const short8*)(sB + off);
    }
#pragma unroll
    for (int i = 0; i < 2; ++i)
#pragma unroll
      for (int j = 0; j < 4; ++j) {
        acc[i][j] = __builtin_amdgcn_mfma_f32_16x16x32_bf16(ah[i], bh[j], acc[i][j], 0, 0, 0);
        acc[i][j] = __builtin_amdgcn_mfma_f32_16x16x32_bf16(al[i], bh[j], acc[i][j], 0, 0, 0);
      }
    __builtin_amdgcn_s_barrier();
  }

  float bj[4];
#pragma unroll
  for (int j = 0; j < 4; ++j) bj[j] = bcat[n0 + wn + j * 16 + l16];
  bool isq = (n0 < 256);
  int cb = n0 - 256;
  int isV = cb >> 8;
  int cc0 = (cb & 255) + wn + l16;
#pragma unroll
  for (int i = 0; i < 2; ++i) {
    int rowb = row0 + wm + i * 16 + quad * 4;
#pragma unroll
    for (int r = 0; r < 4; ++r) {
      int grow = rowb + r;
      if (grow < N_NODES) {
        if (isq) {
          float* cp = qbuf + (size_t)grow * 256 + n0 + wn + l16;
#pragma unroll
          for (int j = 0; j < 4; ++j) cp[j * 16] = acc[i][j][r] + bj[j];
        } else {
          unsigned short* rowp = kv + (size_t)grow * 512 + isV * 4;
#pragma unroll
          for (int j = 0; j < 4; ++j) {
            int c = cc0 + j * 16;
            rowp[((c >> 2) << 3) + (c & 3)] = f2bf(acc[i][j][r] + bj[j]);
          }
        }
      }
    }
  }
}

// ---------------- per-dst-node edge attention (degree-sorted via perm) ----------
__global__ __launch_bounds__(256) void k_attn(
    const float* __restrict__ qbuf, const unsigned short* __restrict__ kv,
    const int* __restrict__ rowstart, const int* __restrict__ packed,
    const int* __restrict__ perm, const float* __restrict__ Eemb_l,
    unsigned short* __restrict__ xhi, unsigned short* __restrict__ xlo) {
  __shared__ float ete_s[NETYPES * 256];
  int t = threadIdx.x;
#pragma unroll
  for (int i = 0; i < NETYPES; ++i) ete_s[i * 256 + t] = Eemb_l[i * 256 + t];
  __syncthreads();
  int lane = t & 63;
  int n = perm[blockIdx.x * 4 + (t >> 6)];
  float4 q4 = ((const float4*)(qbuf + (size_t)n * 256))[lane];
  int rs = rowstart[n], re = rowstart[n + 1];
  float l1 = 0.f, ax1 = 0.f, ay1 = 0.f, az1 = 0.f, aw1 = 0.f;
  float l2 = 0.f, ax2 = 0.f, ay2 = 0.f, az2 = 0.f, aw2 = 0.f;
  int i = rs;
  for (; i + 2 <= re; i += 2) {
    int pkA = packed[i], pkB = packed[i + 1];
    ushort8 cA = ((const ushort8*)(kv + (size_t)(pkA >> 3) * 512))[lane];
    ushort8 cB = ((const ushort8*)(kv + (size_t)(pkB >> 3) * 512))[lane];
    float4 eA = ((const float4*)(ete_s + (pkA & 7) * 256))[lane];
    float4 eB = ((const float4*)(ete_s + (pkB & 7) * 256))[lane];
    float pA = (bf2f(cA[0]) + eA.x) * q4.x + (bf2f(cA[1]) + eA.y) * q4.y +
               (bf2f(cA[2]) + eA.z) * q4.z + (bf2f(cA[3]) + eA.w) * q4.w;
    float pB = (bf2f(cB[0]) + eB.x) * q4.x + (bf2f(cB[1]) + eB.y) * q4.y +
               (bf2f(cB[2]) + eB.z) * q4.z + (bf2f(cB[3]) + eB.w) * q4.w;
    pA = dpp_red_add(pA);
    pB = dpp_red_add(pB);
    float e1 = __expf(pA * 0.125f);
    float e2 = __expf(pB * 0.125f);
    l1 += e1; l2 += e2;
    ax1 = fmaf(e1, bf2f(cA[4]) + eA.x, ax1);
    ay1 = fmaf(e1, bf2f(cA[5]) + eA.y, ay1);
    az1 = fmaf(e1, bf2f(cA[6]) + eA.z, az1);
    aw1 = fmaf(e1, bf2f(cA[7]) + eA.w, aw1);
    ax2 = fmaf(e2, bf2f(cB[4]) + eB.x, ax2);
    ay2 = fmaf(e2, bf2f(cB[5]) + eB.y, ay2);
    az2 = fmaf(e2, bf2f(cB[6]) + eB.z, az2);
    aw2 = fmaf(e2, bf2f(cB[7]) + eB.w, aw2);
  }
  if (i < re) {
    int pk = packed[i];
    ushort8 c = ((const ushort8*)(kv + (size_t)(pk >> 3) * 512))[lane];
    float4 e4 = ((const float4*)(ete_s + (pk & 7) * 256))[lane];
    float p = (bf2f(c[0]) + e4.x) * q4.x + (bf2f(c[1]) + e4.y) * q4.y +
              (bf2f(c[2]) + e4.z) * q4.z + (bf2f(c[3]) + e4.w) * q4.w;
    p = dpp_red_add(p);
    float e1 = __expf(p * 0.125f);
    l1 += e1;
    ax1 = fmaf(e1, bf2f(c[4]) + e4.x, ax1);
    ay1 = fmaf(e1, bf2f(c[5]) + e4.y, ay1);
    az1 = fmaf(e1, bf2f(c[6]) + e4.z, az1);
    aw1 = fmaf(e1, bf2f(c[7]) + e4.w, aw1);
  }
  float l = l1 + l2;
  float inv = 1.f / (l + 1e-16f);
  float4 o;
  o.x = (ax1 + ax2) * inv; o.y = (ay1 + ay2) * inv;
  o.z = (az1 + az2) * inv; o.w = (aw1 + aw2) * inv;
  o.x = o.x > 0.f ? o.x : expm1f(o.x);
  o.y = o.y > 0.f ? o.y : expm1f(o.y);
  o.z = o.z > 0.f ? o.z : expm1f(o.z);
  o.w = o.w > 0.f ? o.w : expm1f(o.w);
  unsigned short h0 = f2bf(o.x), h1 = f2bf(o.y), h2 = f2bf(o.z), h3 = f2bf(o.w);
  ushort4 hv, lv;
  hv.x = h0; hv.y = h1; hv.z = h2; hv.w = h3;
  lv.x = f2bf(o.x - bf2f(h0)); lv.y = f2bf(o.y - bf2f(h1));
  lv.z = f2bf(o.z - bf2f(h2)); lv.w = f2bf(o.w - bf2f(h3));
  size_t base_o = (size_t)n * 256 + lane * 4;
  *(ushort4*)(xhi + base_o) = hv;
  *(ushort4*)(xlo + base_o) = lv;
}

// ---------------- parallel mean pool, stage 1 ----------------
__global__ __launch_bounds__(256) void k_pool_partial(
    const unsigned short* __restrict__ xhi, const unsigned short* __restrict__ xlo,
    const int* __restrict__ batch, float* __restrict__ gacc) {
  int t = threadIdx.x;
  int base = blockIdx.x * 128;
  int end = base + 128; if (end > N_NODES) end = N_NODES;
  __shared__ int bsh[128];
  if (t < 128 && base + t < N_NODES) bsh[t] = batch[base + t];
  __syncthreads();
  float acc = 0.f;
  int cur = bsh[0];
  for (int n = base; n < end; ++n) {
    int g = bsh[n - base];
    if (g != cur) {
      atomicAdd(&gacc[cur * 256 + t], acc);
      acc = 0.f; cur = g;
    }
    size_t idx = (size_t)n * 256 + t;
    acc += bf2f(xhi[idx]) + bf2f(xlo[idx]);
  }
  atomicAdd(&gacc[cur * 256 + t], acc);
}

// ---------------- GRU (h0=0) + FC ----------------
__device__ inline int lower_bound_dev(const int* a, int n, int val) {
  int lo = 0, hi = n;
  while (lo < hi) {
    int mid = (lo + hi) >> 1;
    if (a[mid] < val) lo = mid + 1; else hi = mid;
  }
  return lo;
}

__global__ __launch_bounds__(256) void k_gru_fc(
    const float* __restrict__ gacc, const int* __restrict__ batch,
    const float* __restrict__ W_ih, const float* __restrict__ b_ih,
    const float* __restrict__ b_hh, const float* __restrict__ W_fc,
    const float* __restrict__ b_fc, float* __restrict__ out) {
  __shared__ float gv[256];
  __shared__ float gates[192];
  __shared__ float h[64];
  int gr = blockIdx.x, t = threadIdx.x;
  int s0 = lower_bound_dev(batch, N_NODES, gr);
  int e0 = lower_bound_dev(batch, N_NODES, gr + 1);
  float c = (e0 > s0) ? (float)(e0 - s0) : 1.f;
  gv[t] = gacc[gr * 256 + t] / c;
  __syncthreads();
  if (t < 192) {
    const float* wr = W_ih + t * 256;
    float s = b_ih[t];
    for (int k = 0; k < 256; ++k) s = fmaf(gv[k], wr[k], s);
    gates[t] = s;
  }
  __syncthreads();
  if (t < 64) {
    float r  = 1.f / (1.f + expf(-(gates[t] + b_hh[t])));
    float z  = 1.f / (1.f + expf(-(gates[64 + t] + b_hh[64 + t])));
    float nn = tanhf(gates[128 + t] + r * b_hh[128 + t]);
    h[t] = (1.f - z) * nn;
  }
  __syncthreads();
  if (t < 2) {
    const float* wr = W_fc + t * 64;
    float s = b_fc[t];
    for (int k = 0; k < 64; ++k) s = fmaf(h[k], wr[k], s);
    out[gr * 2 + t] = s;
  }
}

extern "C" void kernel_launch(void* const* d_in, const int* in_sizes, int n_in,
                              void* d_out, int out_size, void* d_ws, size_t ws_size,
                              hipStream_t stream) {
  const float* x     = (const float*)d_in[0];
  const int* edge_index = (const int*)d_in[1];
  const int* batch   = (const int*)d_in[2];
  const int* etype   = (const int*)d_in[3];
  const float* Wq    = (const float*)d_in[4];
  const float* bq    = (const float*)d_in[5];
  const float* Wk    = (const float*)d_in[6];
  const float* bk    = (const float*)d_in[7];
  const float* Wv    = (const float*)d_in[8];
  const float* bv    = (const float*)d_in[9];
  const float* Eemb  = (const float*)d_in[10];
  const float* W_ih  = (const float*)d_in[11];
  const float* b_ih  = (const float*)d_in[12];
  const float* b_hh  = (const float*)d_in[14];
  const float* W_fc  = (const float*)d_in[15];
  const float* b_fc  = (const float*)d_in[16];
  float* out = (float*)d_out;

  const int* src = edge_index;
  const int* dst = edge_index + N_EDGES;

  float* qbuf  = (float*)d_ws;                             // N*256 f32
  float* gacc  = qbuf + (size_t)N_NODES * 256;             // 64*256
  float* bcat  = gacc + NGRAPHS * 256;                     // 3*768
  unsigned short* kv   = (unsigned short*)(bcat + NLAYERS * 768);  // N*512 bf16
  unsigned short* xhi  = kv + (size_t)N_NODES * 512;       // N*256
  unsigned short* xlo  = xhi + (size_t)N_NODES * 256;
  unsigned short* wthi = xlo + (size_t)N_NODES * 256;      // 3*768*256
  int* deg      = (int*)(wthi + (size_t)NLAYERS * 768 * 256);
  int* rowstart = deg + N_NODES;
  int* cursor   = rowstart + N_NODES + 1;
  int* packed   = cursor + N_NODES;
  int* perm     = packed + N_EDGES;
  int* bcur_g   = perm + N_NODES;

  hipMemsetAsync(deg, 0, N_NODES * sizeof(int), stream);
  k_prep<<<PREP_BLOCKS, 256, 0, stream>>>(dst, deg, x, xhi, xlo,
                                          Wq, Wk, Wv, wthi, bq, bk, bv, bcat, gacc);
  k_scan_sort<<<1, 1024, 0, stream>>>(deg, rowstart, cursor, bcur_g);
  k_scatter<<<SCAT_EB + SCAT_NB, 256, 0, stream>>>(src, dst, etype, cursor, packed,
                                                   deg, bcur_g, perm);

  for (int l = 0; l < NLAYERS; ++l) {
    k_gemm_mfma<<<59 * 8 * 6, 256, 0, stream>>>(
        xhi, xlo, wthi + (size_t)l * 768 * 256,
        bcat + l * 768, qbuf, kv);
    k_attn<<<N_NODES / 4, 256, 0, stream>>>(qbuf, kv, rowstart, packed, perm,
                                            Eemb + (size_t)l * NETYPES * 256, xhi, xlo);
  }
  k_pool_partial<<<(N_NODES + 127) / 128, 256, 0, stream>>>(xhi, xlo, batch, gacc);
  k_gru_fc<<<NGRAPHS, 256, 0, stream>>>(gacc, batch, W_ih, b_ih, b_hh, W_fc, b_fc, out);
}

// Round 10
// 453.767 us; speedup vs baseline: 1.2039x; 1.0065x over previous
//
#include <hip/hip_runtime.h>
#include <math.h>

#define N_NODES 30000
#define N_EDGES 240000
#define DMODEL 256
#define NETYPES 8
#define NGRAPHS 64
#define NLAYERS 3

typedef __attribute__((ext_vector_type(8))) short short8;
typedef __attribute__((ext_vector_type(8))) unsigned short ushort8;
typedef __attribute__((ext_vector_type(4))) float f32x4;

// ---- bf16 split helpers (round-to-nearest-even) ----
__device__ __forceinline__ unsigned short f2bf(float f) {
  union { float f; unsigned u; } v; v.f = f;
  unsigned r = v.u + 0x7FFF + ((v.u >> 16) & 1);
  return (unsigned short)(r >> 16);
}
__device__ __forceinline__ float bf2f(unsigned short h) {
  union { unsigned u; float f; } v; v.u = ((unsigned)h) << 16;
  return v.f;
}

__device__ __forceinline__ void async_g2l(const unsigned short* g, unsigned short* l) {
  __builtin_amdgcn_global_load_lds(
      (const __attribute__((address_space(1))) void*)g,
      (__attribute__((address_space(3))) void*)l, 16, 0, 0);
}

// 16-lane (intra-head) sum via DPP.
__device__ __forceinline__ float dpp_red_add(float x) {
  int v = __float_as_int(x);
  int t;
  t = __builtin_amdgcn_update_dpp(0, v, 0xB1, 0xF, 0xF, true);   // quad_perm [1,0,3,2]
  v = __float_as_int(__int_as_float(v) + __int_as_float(t));
  t = __builtin_amdgcn_update_dpp(0, v, 0x4E, 0xF, 0xF, true);   // quad_perm [2,3,0,1]
  v = __float_as_int(__int_as_float(v) + __int_as_float(t));
  t = __builtin_amdgcn_update_dpp(0, v, 0x141, 0xF, 0xF, true);  // row_half_mirror (^7)
  v = __float_as_int(__int_as_float(v) + __int_as_float(t));
  t = __builtin_amdgcn_update_dpp(0, v, 0x140, 0xF, 0xF, true);  // row_mirror (^15)
  v = __float_as_int(__int_as_float(v) + __int_as_float(t));
  return __int_as_float(v);
}

// ---------------- fused prologue: count_deg | cvt_x | cvt_w | cvt_b | zero gacc ----
#define PREP_CNT 938
#define PREP_CVTX 3750
#define PREP_CVTW 576
#define PREP_CVTB 9
#define PREP_GACC 64
#define B_CVTX (PREP_CNT)
#define B_CVTW (B_CVTX + PREP_CVTX)
#define B_CVTB (B_CVTW + PREP_CVTW)
#define B_GACC (B_CVTB + PREP_CVTB)
#define PREP_BLOCKS (B_GACC + PREP_GACC)

__global__ __launch_bounds__(256) void k_prep(
    const int* __restrict__ dst, int* __restrict__ deg,
    const float* __restrict__ x, unsigned short* __restrict__ xhi,
    unsigned short* __restrict__ xlo,
    const float* __restrict__ Wq, const float* __restrict__ Wk,
    const float* __restrict__ Wv, unsigned short* __restrict__ wthi,
    const float* __restrict__ bq, const float* __restrict__ bk,
    const float* __restrict__ bv, float* __restrict__ bcat,
    float* __restrict__ gacc) {
  __shared__ float tile[32][33];
  int bid = blockIdx.x, t = threadIdx.x;
  if (bid < PREP_CNT) {
    int e = bid * 256 + t;
    if (e < N_EDGES) atomicAdd(&deg[dst[e]], 1);
  } else if (bid < B_CVTW) {
    size_t i0 = ((size_t)(bid - B_CVTX) * 256 + t) * 8;
#pragma unroll
    for (int h = 0; h < 2; ++h) {
      float4 v4 = *(const float4*)(x + i0 + h * 4);
      ushort4 hv, lv;
      hv.x = f2bf(v4.x); lv.x = f2bf(v4.x - bf2f(hv.x));
      hv.y = f2bf(v4.y); lv.y = f2bf(v4.y - bf2f(hv.y));
      hv.z = f2bf(v4.z); lv.z = f2bf(v4.z - bf2f(hv.z));
      hv.w = f2bf(v4.w); lv.w = f2bf(v4.w - bf2f(hv.w));
      *(ushort4*)(xhi + i0 + h * 4) = hv;
      *(ushort4*)(xlo + i0 + h * 4) = lv;
    }
  } else if (bid < B_CVTB) {
    int rel = bid - B_CVTW;
    int k0 = (rel & 7) * 32;
    int n0g = ((rel >> 3) % 24) * 32;
    int l = rel / 192;
    int which = n0g >> 8;
    int col0 = n0g & 255;
    const float* W = (which == 0) ? Wq : ((which == 1) ? Wk : Wv);
    int c = t & 31, r = t >> 5;
#pragma unroll
    for (int rr = 0; rr < 4; ++rr) {
      int kk = r + rr * 8;
      tile[kk][c] = W[(size_t)l * 65536 + (size_t)(k0 + kk) * 256 + col0 + c];
    }
    __syncthreads();
    int kk = t & 31, nn0 = t >> 5;
#pragma unroll
    for (int rr = 0; rr < 4; ++rr) {
      int nn = nn0 + rr * 8;
      wthi[((size_t)l * 768 + n0g + nn) * 256 + k0 + kk] = f2bf(tile[kk][nn]);
    }
  } else if (bid < B_GACC) {
    int idx = (bid - B_CVTB) * 256 + t;
    if (idx < NLAYERS * 768) {
      int n = idx % 768, l = idx / 768;
      int which = n >> 8, col = n & 255;
      const float* b = (which == 0) ? bq : ((which == 1) ? bk : bv);
      bcat[idx] = b[l * 256 + col];
    }
  } else {
    int idx = (bid - B_GACC) * 256 + t;
    gacc[idx] = 0.f;
  }
}

// ---------------- scan + histogram (8 sub-hists to kill hot-bucket LDS atomics) ----
__global__ __launch_bounds__(1024) void k_scan_sort(
    const int* __restrict__ deg, int* __restrict__ rowstart,
    int* __restrict__ cursor, int* __restrict__ bcur_g) {
  const int C = 30;
  __shared__ int hist8[8][256];   // one per wave-pair: contention / 8
  __shared__ int hist[256];
  int tid = threadIdx.x;
  int sub = tid >> 7;             // 0..7
#pragma unroll
  for (int k = tid; k < 8 * 256; k += 1024) ((int*)hist8)[k] = 0;
  __syncthreads();
  int base = tid * C;
  int vals[C];
  int sum = 0;
#pragma unroll
  for (int j = 0; j < C; ++j) {
    int idx = base + j;
    int v = (idx < N_NODES) ? deg[idx] : 0;
    if (idx < N_NODES) {
      int d = v > 255 ? 255 : v;
      atomicAdd(&hist8[sub][d], 1);
    }
    vals[j] = sum;
    sum += v;
  }
  int lane = tid & 63, wv = tid >> 6;
  int s = sum;
#pragma unroll
  for (int off = 1; off < 64; off <<= 1) {
    int t2 = __shfl_up(s, off);
    if (lane >= off) s += t2;
  }
  __shared__ int wsum[16];
  if (lane == 63) wsum[wv] = s;
  __syncthreads();
  if (tid < 256) {
    int a = 0;
#pragma unroll
    for (int k = 0; k < 8; ++k) a += hist8[k][tid];
    hist[tid] = a;
  }
  __syncthreads();
  if (tid == 0) {
    int a = 0;
#pragma unroll
    for (int i = 0; i < 16; ++i) { int t2 = wsum[i]; wsum[i] = a; a += t2; }
    rowstart[N_NODES] = a;
    // descending exclusive scan of hist -> bucket starts
    int b = 0;
    for (int d = 255; d >= 0; --d) { int h = hist[d]; hist[d] = b; b += h; }
  }
  __syncthreads();
  int texcl = wsum[wv] + (s - sum);
#pragma unroll
  for (int j = 0; j < C; ++j) {
    int idx = base + j;
    if (idx < N_NODES) {
      int p = texcl + vals[j];
      rowstart[idx] = p;
      cursor[idx]   = p;
    }
  }
  if (tid < 256) bcur_g[tid] = hist[tid];
}

// ---------------- edge scatter + two-level perm placement ----------------
#define SCAT_EB ((N_EDGES + 255) / 256)   // 938
#define SCAT_NB ((N_NODES + 255) / 256)   // 118
__global__ __launch_bounds__(256) void k_scatter(
    const int* __restrict__ src, const int* __restrict__ dst,
    const int* __restrict__ etype, int* __restrict__ cursor,
    int* __restrict__ packed, const int* __restrict__ deg,
    int* __restrict__ bcur_g, int* __restrict__ perm) {
  int bid = blockIdx.x;
  int t = threadIdx.x;
  if (bid < SCAT_EB) {
    int e = bid * 256 + t;
    if (e < N_EDGES) {
      int p = atomicAdd(&cursor[dst[e]], 1);
      packed[p] = src[e] * NETYPES + etype[e];
    }
  } else {
    __shared__ int hist[256], lbase[256], lcur[256];
    hist[t] = 0;
    lcur[t] = 0;
    __syncthreads();
    int i = (bid - SCAT_EB) * 256 + t;
    int d = 0;
    bool valid = (i < N_NODES);
    if (valid) {
      d = deg[i]; if (d > 255) d = 255;
      atomicAdd(&hist[d], 1);
    }
    __syncthreads();
    int h = hist[t];
    if (h > 0) lbase[t] = atomicAdd(&bcur_g[t], h);
    __syncthreads();
    if (valid) {
      int r = atomicAdd(&lcur[d], 1);
      perm[lbase[d] + r] = i;
    }
  }
}

// ---------------- split-bf16 MFMA GEMM, 2-term (Ahi*Bhi + Alo*Bhi) ----------
__global__ __launch_bounds__(256, 5) void k_gemm_mfma(
    const unsigned short* __restrict__ Ahi, const unsigned short* __restrict__ Alo,
    const unsigned short* __restrict__ Bhi,
    const float* __restrict__ bcat, float* __restrict__ qbuf,
    unsigned short* __restrict__ kv) {
  __shared__ unsigned short smem[2 * 8192];

  int tid = threadIdx.x;
  int lane = tid & 63, wave = tid >> 6;
  int bx = blockIdx.x;
  int xcd = bx & 7, slot = bx >> 3;
  int rt = xcd + (slot / 6) * 8;
  if (rt >= 469) return;
  int row0 = rt * 64;
  int n0 = (slot % 6) * 128;
  int wm = (wave >> 1) * 32, wn = (wave & 1) * 64;
  int quad = lane >> 4, l16 = lane & 15;
  int lrow = lane >> 2;
  int chSw = (lane & 3) ^ ((lane >> 3) & 3);
  int rdSw = (quad ^ ((l16 >> 1) & 3)) * 8;

  f32x4 acc[2][4];
#pragma unroll
  for (int i = 0; i < 2; ++i)
#pragma unroll
    for (int j = 0; j < 4; ++j) acc[i][j] = (f32x4)(0.f);

  auto STAGE = [&](int k0, int b) {
    unsigned short* s = smem + b * 8192;
    int garA = row0 + wave * 16 + lrow; if (garA >= N_NODES) garA = N_NODES - 1;
    size_t acol = (size_t)garA * 256 + k0 + chSw * 8;
    async_g2l(Ahi + acol, s + wave * 512);
    async_g2l(Alo + acol, s + 2048 + wave * 512);
#pragma unroll
    for (int r = 0; r < 2; ++r) {
      int brow = r * 64 + wave * 16 + lrow;
      size_t boff = (size_t)(n0 + brow) * 256 + k0 + chSw * 8;
      async_g2l(Bhi + boff, s + 4096 + r * 2048 + wave * 512);
    }
  };

  STAGE(0, 0);
#pragma unroll
  for (int k = 0; k < 8; ++k) {
    int cur = k & 1;
    if (k < 7) {
      STAGE((k + 1) * 32, cur ^ 1);
      asm volatile("s_waitcnt vmcnt(4)" ::: "memory");
    } else {
      asm volatile("s_waitcnt vmcnt(0)" ::: "memory");
    }
    __builtin_amdgcn_s_barrier();

    const unsigned short* sAhi = smem + cur * 8192;
    const unsigned short* sAlo = sAhi + 2048;
    const unsigned short* sB   = sAhi + 4096;
    short8 ah[2], al[2], bh[4];
#pragma unroll
    for (int i = 0; i < 2; ++i) {
      int off = (wm + i * 16 + l16) * 32 + rdSw;
      ah[i] = *(const short8*)(sAhi + off);
      al[i] = *(const short8*)(sAlo + off);
    }
#pragma unroll
    for (int j = 0; j < 4; ++j) {
      int off = (wn + j * 16 + l16) * 32 + rdSw;
      bh[j] = *(const short8*)(sB + off);
    }
#pragma unroll
    for (int i = 0; i < 2; ++i)
#pragma unroll
      for (int j = 0; j < 4; ++j) {
        acc[i][j] = __builtin_amdgcn_mfma_f32_16x16x32_bf16(ah[i], bh[j], acc[i][j], 0, 0, 0);
        acc[i][j] = __builtin_amdgcn_mfma_f32_16x16x32_bf16(al[i], bh[j], acc[i][j], 0, 0, 0);
      }
    __builtin_amdgcn_s_barrier();
  }

  float bj[4];
#pragma unroll
  for (int j = 0; j < 4; ++j) bj[j] = bcat[n0 + wn + j * 16 + l16];
  bool isq = (n0 < 256);
  int cb = n0 - 256;
  int isV = cb >> 8;
  int cc0 = (cb & 255) + wn + l16;
#pragma unroll
  for (int i = 0; i < 2; ++i) {
    int rowb = row0 + wm + i * 16 + quad * 4;
#pragma unroll
    for (int r = 0; r < 4; ++r) {
      int grow = rowb + r;
      if (grow < N_NODES) {
        if (isq) {
          float* cp = qbuf + (size_t)grow * 256 + n0 + wn + l16;
#pragma unroll
          for (int j = 0; j < 4; ++j) cp[j * 16] = acc[i][j][r] + bj[j];
        } else {
          unsigned short* rowp = kv + (size_t)grow * 512 + isV * 4;
#pragma unroll
          for (int j = 0; j < 4; ++j) {
            int c = cc0 + j * 16;
            rowp[((c >> 2) << 3) + (c & 3)] = f2bf(acc[i][j][r] + bj[j]);
          }
        }
      }
    }
  }
}

// ---------------- per-dst-node edge attention (degree-sorted via perm) ----------
__global__ __launch_bounds__(256) void k_attn(
    const float* __restrict__ qbuf, const unsigned short* __restrict__ kv,
    const int* __restrict__ rowstart, const int* __restrict__ packed,
    const int* __restrict__ perm, const float* __restrict__ Eemb_l,
    unsigned short* __restrict__ xhi, unsigned short* __restrict__ xlo) {
  __shared__ float ete_s[NETYPES * 256];
  int t = threadIdx.x;
#pragma unroll
  for (int i = 0; i < NETYPES; ++i) ete_s[i * 256 + t] = Eemb_l[i * 256 + t];
  __syncthreads();
  int lane = t & 63;
  int n = perm[blockIdx.x * 4 + (t >> 6)];
  float4 q4 = ((const float4*)(qbuf + (size_t)n * 256))[lane];
  int rs = rowstart[n], re = rowstart[n + 1];
  float l1 = 0.f, ax1 = 0.f, ay1 = 0.f, az1 = 0.f, aw1 = 0.f;
  float l2 = 0.f, ax2 = 0.f, ay2 = 0.f, az2 = 0.f, aw2 = 0.f;
  int i = rs;
  for (; i + 2 <= re; i += 2) {
    int pkA = packed[i], pkB = packed[i + 1];
    ushort8 cA = ((const ushort8*)(kv + (size_t)(pkA >> 3) * 512))[lane];
    ushort8 cB = ((const ushort8*)(kv + (size_t)(pkB >> 3) * 512))[lane];
    float4 eA = ((const float4*)(ete_s + (pkA & 7) * 256))[lane];
    float4 eB = ((const float4*)(ete_s + (pkB & 7) * 256))[lane];
    float pA = (bf2f(cA[0]) + eA.x) * q4.x + (bf2f(cA[1]) + eA.y) * q4.y +
               (bf2f(cA[2]) + eA.z) * q4.z + (bf2f(cA[3]) + eA.w) * q4.w;
    float pB = (bf2f(cB[0]) + eB.x) * q4.x + (bf2f(cB[1]) + eB.y) * q4.y +
               (bf2f(cB[2]) + eB.z) * q4.z + (bf2f(cB[3]) + eB.w) * q4.w;
    pA = dpp_red_add(pA);
    pB = dpp_red_add(pB);
    float e1 = __expf(pA * 0.125f);
    float e2 = __expf(pB * 0.125f);
    l1 += e1; l2 += e2;
    ax1 = fmaf(e1, bf2f(cA[4]) + eA.x, ax1);
    ay1 = fmaf(e1, bf2f(cA[5]) + eA.y, ay1);
    az1 = fmaf(e1, bf2f(cA[6]) + eA.z, az1);
    aw1 = fmaf(e1, bf2f(cA[7]) + eA.w, aw1);
    ax2 = fmaf(e2, bf2f(cB[4]) + eB.x, ax2);
    ay2 = fmaf(e2, bf2f(cB[5]) + eB.y, ay2);
    az2 = fmaf(e2, bf2f(cB[6]) + eB.z, az2);
    aw2 = fmaf(e2, bf2f(cB[7]) + eB.w, aw2);
  }
  if (i < re) {
    int pk = packed[i];
    ushort8 c = ((const ushort8*)(kv + (size_t)(pk >> 3) * 512))[lane];
    float4 e4 = ((const float4*)(ete_s + (pk & 7) * 256))[lane];
    float p = (bf2f(c[0]) + e4.x) * q4.x + (bf2f(c[1]) + e4.y) * q4.y +
              (bf2f(c[2]) + e4.z) * q4.z + (bf2f(c[3]) + e4.w) * q4.w;
    p = dpp_red_add(p);
    float e1 = __expf(p * 0.125f);
    l1 += e1;
    ax1 = fmaf(e1, bf2f(c[4]) + e4.x, ax1);
    ay1 = fmaf(e1, bf2f(c[5]) + e4.y, ay1);
    az1 = fmaf(e1, bf2f(c[6]) + e4.z, az1);
    aw1 = fmaf(e1, bf2f(c[7]) + e4.w, aw1);
  }
  float l = l1 + l2;
  float inv = 1.f / (l + 1e-16f);
  float4 o;
  o.x = (ax1 + ax2) * inv; o.y = (ay1 + ay2) * inv;
  o.z = (az1 + az2) * inv; o.w = (aw1 + aw2) * inv;
  o.x = o.x > 0.f ? o.x : expm1f(o.x);
  o.y = o.y > 0.f ? o.y : expm1f(o.y);
  o.z = o.z > 0.f ? o.z : expm1f(o.z);
  o.w = o.w > 0.f ? o.w : expm1f(o.w);
  unsigned short h0 = f2bf(o.x), h1 = f2bf(o.y), h2 = f2bf(o.z), h3 = f2bf(o.w);
  ushort4 hv, lv;
  hv.x = h0; hv.y = h1; hv.z = h2; hv.w = h3;
  lv.x = f2bf(o.x - bf2f(h0)); lv.y = f2bf(o.y - bf2f(h1));
  lv.z = f2bf(o.z - bf2f(h2)); lv.w = f2bf(o.w - bf2f(h3));
  size_t base_o = (size_t)n * 256 + lane * 4;
  *(ushort4*)(xhi + base_o) = hv;
  *(ushort4*)(xlo + base_o) = lv;
}

// ---------------- parallel mean pool, stage 1 ----------------
__global__ __launch_bounds__(256) void k_pool_partial(
    const unsigned short* __restrict__ xhi, const unsigned short* __restrict__ xlo,
    const int* __restrict__ batch, float* __restrict__ gacc) {
  int t = threadIdx.x;
  int base = blockIdx.x * 128;
  int end = base + 128; if (end > N_NODES) end = N_NODES;
  __shared__ int bsh[128];
  if (t < 128 && base + t < N_NODES) bsh[t] = batch[base + t];
  __syncthreads();
  float acc = 0.f;
  int cur = bsh[0];
  for (int n = base; n < end; ++n) {
    int g = bsh[n - base];
    if (g != cur) {
      atomicAdd(&gacc[cur * 256 + t], acc);
      acc = 0.f; cur = g;
    }
    size_t idx = (size_t)n * 256 + t;
    acc += bf2f(xhi[idx]) + bf2f(xlo[idx]);
  }
  atomicAdd(&gacc[cur * 256 + t], acc);
}

// ---------------- GRU (h0=0) + FC ----------------
__device__ inline int lower_bound_dev(const int* a, int n, int val) {
  int lo = 0, hi = n;
  while (lo < hi) {
    int mid = (lo + hi) >> 1;
    if (a[mid] < val) lo = mid + 1; else hi = mid;
  }
  return lo;
}

__global__ __launch_bounds__(256) void k_gru_fc(
    const float* __restrict__ gacc, const int* __restrict__ batch,
    const float* __restrict__ W_ih, const float* __restrict__ b_ih,
    const float* __restrict__ b_hh, const float* __restrict__ W_fc,
    const float* __restrict__ b_fc, float* __restrict__ out) {
  __shared__ float gv[256];
  __shared__ float gates[192];
  __shared__ float h[64];
  int gr = blockIdx.x, t = threadIdx.x;
  int s0 = lower_bound_dev(batch, N_NODES, gr);
  int e0 = lower_bound_dev(batch, N_NODES, gr + 1);
  float c = (e0 > s0) ? (float)(e0 - s0) : 1.f;
  gv[t] = gacc[gr * 256 + t] / c;
  __syncthreads();
  if (t < 192) {
    const float* wr = W_ih + t * 256;
    float s = b_ih[t];
    for (int k = 0; k < 256; ++k) s = fmaf(gv[k], wr[k], s);
    gates[t] = s;
  }
  __syncthreads();
  if (t < 64) {
    float r  = 1.f / (1.f + expf(-(gates[t] + b_hh[t])));
    float z  = 1.f / (1.f + expf(-(gates[64 + t] + b_hh[64 + t])));
    float nn = tanhf(gates[128 + t] + r * b_hh[128 + t]);
    h[t] = (1.f - z) * nn;
  }
  __syncthreads();
  if (t < 2) {
    const float* wr = W_fc + t * 64;
    float s = b_fc[t];
    for (int k = 0; k < 64; ++k) s = fmaf(h[k], wr[k], s);
    out[gr * 2 + t] = s;
  }
}

extern "C" void kernel_launch(void* const* d_in, const int* in_sizes, int n_in,
                              void* d_out, int out_size, void* d_ws, size_t ws_size,
                              hipStream_t stream) {
  const float* x     = (const float*)d_in[0];
  const int* edge_index = (const int*)d_in[1];
  const int* batch   = (const int*)d_in[2];
  const int* etype   = (const int*)d_in[3];
  const float* Wq    = (const float*)d_in[4];
  const float* bq    = (const float*)d_in[5];
  const float* Wk    = (const float*)d_in[6];
  const float* bk    = (const float*)d_in[7];
  const float* Wv    = (const float*)d_in[8];
  const float* bv    = (const float*)d_in[9];
  const float* Eemb  = (const float*)d_in[10];
  const float* W_ih  = (const float*)d_in[11];
  const float* b_ih  = (const float*)d_in[12];
  const float* b_hh  = (const float*)d_in[14];
  const float* W_fc  = (const float*)d_in[15];
  const float* b_fc  = (const float*)d_in[16];
  float* out = (float*)d_out;

  const int* src = edge_index;
  const int* dst = edge_index + N_EDGES;

  float* qbuf  = (float*)d_ws;                             // N*256 f32
  float* gacc  = qbuf + (size_t)N_NODES * 256;             // 64*256
  float* bcat  = gacc + NGRAPHS * 256;                     // 3*768
  unsigned short* kv   = (unsigned short*)(bcat + NLAYERS * 768);  // N*512 bf16
  unsigned short* xhi  = kv + (size_t)N_NODES * 512;       // N*256
  unsigned short* xlo  = xhi + (size_t)N_NODES * 256;
  unsigned short* wthi = xlo + (size_t)N_NODES * 256;      // 3*768*256
  int* deg      = (int*)(wthi + (size_t)NLAYERS * 768 * 256);
  int* rowstart = deg + N_NODES;
  int* cursor   = rowstart + N_NODES + 1;
  int* packed   = cursor + N_NODES;
  int* perm     = packed + N_EDGES;
  int* bcur_g   = perm + N_NODES;

  hipMemsetAsync(deg, 0, N_NODES * sizeof(int), stream);
  k_prep<<<PREP_BLOCKS, 256, 0, stream>>>(dst, deg, x, xhi, xlo,
                                          Wq, Wk, Wv, wthi, bq, bk, bv, bcat, gacc);
  k_scan_sort<<<1, 1024, 0, stream>>>(deg, rowstart, cursor, bcur_g);
  k_scatter<<<SCAT_EB + SCAT_NB, 256, 0, stream>>>(src, dst, etype, cursor, packed,
                                                   deg, bcur_g, perm);

  for (int l = 0; l < NLAYERS; ++l) {
    k_gemm_mfma<<<59 * 8 * 6, 256, 0, stream>>>(
        xhi, xlo, wthi + (size_t)l * 768 * 256,
        bcat + l * 768, qbuf, kv);
    k_attn<<<N_NODES / 4, 256, 0, stream>>>(qbuf, kv, rowstart, packed, perm,
                                            Eemb + (size_t)l * NETYPES * 256, xhi, xlo);
  }
  k_pool_partial<<<(N_NODES + 127) / 128, 256, 0, stream>>>(xhi, xlo, batch, gacc);
  k_gru_fc<<<NGRAPHS, 256, 0, stream>>>(gacc, batch, W_ih, b_ih, b_hh, W_fc, b_fc, out);
}

// Round 11
// 446.302 us; speedup vs baseline: 1.2240x; 1.0167x over previous
//
#include <hip/hip_runtime.h>
#include <math.h>

#define N_NODES 30000
#define N_EDGES 240000
#define DMODEL 256
#define NETYPES 8
#define NGRAPHS 64
#define NLAYERS 3

typedef __attribute__((ext_vector_type(8))) short short8;
typedef __attribute__((ext_vector_type(8))) unsigned short ushort8;
typedef __attribute__((ext_vector_type(4))) float f32x4;

// ---- bf16 split helpers (round-to-nearest-even) ----
__device__ __forceinline__ unsigned short f2bf(float f) {
  union { float f; unsigned u; } v; v.f = f;
  unsigned r = v.u + 0x7FFF + ((v.u >> 16) & 1);
  return (unsigned short)(r >> 16);
}
__device__ __forceinline__ float bf2f(unsigned short h) {
  union { unsigned u; float f; } v; v.u = ((unsigned)h) << 16;
  return v.f;
}

__device__ __forceinline__ void async_g2l(const unsigned short* g, unsigned short* l) {
  __builtin_amdgcn_global_load_lds(
      (const __attribute__((address_space(1))) void*)g,
      (__attribute__((address_space(3))) void*)l, 16, 0, 0);
}

// 16-lane (intra-head) sum via DPP.
__device__ __forceinline__ float dpp_red_add(float x) {
  int v = __float_as_int(x);
  int t;
  t = __builtin_amdgcn_update_dpp(0, v, 0xB1, 0xF, 0xF, true);   // quad_perm [1,0,3,2]
  v = __float_as_int(__int_as_float(v) + __int_as_float(t));
  t = __builtin_amdgcn_update_dpp(0, v, 0x4E, 0xF, 0xF, true);   // quad_perm [2,3,0,1]
  v = __float_as_int(__int_as_float(v) + __int_as_float(t));
  t = __builtin_amdgcn_update_dpp(0, v, 0x141, 0xF, 0xF, true);  // row_half_mirror (^7)
  v = __float_as_int(__int_as_float(v) + __int_as_float(t));
  t = __builtin_amdgcn_update_dpp(0, v, 0x140, 0xF, 0xF, true);  // row_mirror (^15)
  v = __float_as_int(__int_as_float(v) + __int_as_float(t));
  return __int_as_float(v);
}

// ---------------- fused prologue: count_deg | cvt_x | cvt_w | cvt_b | zero gacc ----
#define PREP_CNT 938
#define PREP_CVTX 3750
#define PREP_CVTW 576
#define PREP_CVTB 9
#define PREP_GACC 64
#define B_CVTX (PREP_CNT)
#define B_CVTW (B_CVTX + PREP_CVTX)
#define B_CVTB (B_CVTW + PREP_CVTW)
#define B_GACC (B_CVTB + PREP_CVTB)
#define PREP_BLOCKS (B_GACC + PREP_GACC)

__global__ __launch_bounds__(256) void k_prep(
    const int* __restrict__ dst, int* __restrict__ deg,
    const float* __restrict__ x, unsigned short* __restrict__ xhi,
    unsigned short* __restrict__ xlo,
    const float* __restrict__ Wq, const float* __restrict__ Wk,
    const float* __restrict__ Wv, unsigned short* __restrict__ wthi,
    const float* __restrict__ bq, const float* __restrict__ bk,
    const float* __restrict__ bv, float* __restrict__ bcat,
    float* __restrict__ gacc) {
  __shared__ float tile[32][33];
  int bid = blockIdx.x, t = threadIdx.x;
  if (bid < PREP_CNT) {
    int e = bid * 256 + t;
    if (e < N_EDGES) atomicAdd(&deg[dst[e]], 1);
  } else if (bid < B_CVTW) {
    size_t i0 = ((size_t)(bid - B_CVTX) * 256 + t) * 8;
#pragma unroll
    for (int h = 0; h < 2; ++h) {
      float4 v4 = *(const float4*)(x + i0 + h * 4);
      ushort4 hv, lv;
      hv.x = f2bf(v4.x); lv.x = f2bf(v4.x - bf2f(hv.x));
      hv.y = f2bf(v4.y); lv.y = f2bf(v4.y - bf2f(hv.y));
      hv.z = f2bf(v4.z); lv.z = f2bf(v4.z - bf2f(hv.z));
      hv.w = f2bf(v4.w); lv.w = f2bf(v4.w - bf2f(hv.w));
      *(ushort4*)(xhi + i0 + h * 4) = hv;
      *(ushort4*)(xlo + i0 + h * 4) = lv;
    }
  } else if (bid < B_CVTB) {
    int rel = bid - B_CVTW;
    int k0 = (rel & 7) * 32;
    int n0g = ((rel >> 3) % 24) * 32;
    int l = rel / 192;
    int which = n0g >> 8;
    int col0 = n0g & 255;
    const float* W = (which == 0) ? Wq : ((which == 1) ? Wk : Wv);
    int c = t & 31, r = t >> 5;
#pragma unroll
    for (int rr = 0; rr < 4; ++rr) {
      int kk = r + rr * 8;
      tile[kk][c] = W[(size_t)l * 65536 + (size_t)(k0 + kk) * 256 + col0 + c];
    }
    __syncthreads();
    int kk = t & 31, nn0 = t >> 5;
#pragma unroll
    for (int rr = 0; rr < 4; ++rr) {
      int nn = nn0 + rr * 8;
      wthi[((size_t)l * 768 + n0g + nn) * 256 + k0 + kk] = f2bf(tile[kk][nn]);
    }
  } else if (bid < B_GACC) {
    int idx = (bid - B_CVTB) * 256 + t;
    if (idx < NLAYERS * 768) {
      int n = idx % 768, l = idx / 768;
      int which = n >> 8, col = n & 255;
      const float* b = (which == 0) ? bq : ((which == 1) ? bk : bv);
      bcat[idx] = b[l * 256 + col];
    }
  } else {
    int idx = (bid - B_GACC) * 256 + t;
    gacc[idx] = 0.f;
  }
}

// ---------------- coalesced scan (transposed order) + histogram ----------------
// r10 postmortem: 46us was NOT histogram atomics (identical time & conflicts
// with 1 vs 8 sub-hists) — it was stride-30 per-thread chunks: every wave
// load/store touched 64 cache lines through one CU's L1. Fix: element
// (j*1024+tid) per round — fully coalesced. rowstart need not be monotone in
// node order (attn uses re = rs + deg[n]); any disjoint allocation works.
__global__ __launch_bounds__(1024) void k_scan_sort(
    const int* __restrict__ deg, int* __restrict__ rowstart,
    int* __restrict__ cursor, int* __restrict__ bcur_g) {
  const int R = 30;                 // 30*1024 = 30720 >= N_NODES
  __shared__ int hist8[8][256];
  __shared__ int hist[256];
  __shared__ int wpart[2][16];
  int tid = threadIdx.x;
  int lane = tid & 63, wv = tid >> 6;
  int sub = tid >> 7;
  for (int k = tid; k < 8 * 256; k += 1024) ((int*)hist8)[k] = 0;
  __syncthreads();
  int carry = 0;
  for (int j = 0; j < R; ++j) {
    int idx = j * 1024 + tid;       // coalesced: lane-contiguous
    int v = (idx < N_NODES) ? deg[idx] : 0;
    if (idx < N_NODES) {
      int d = v > 255 ? 255 : v;
      atomicAdd(&hist8[sub][d], 1);
    }
    int s = v;                      // wave-inclusive scan
#pragma unroll
    for (int off = 1; off < 64; off <<= 1) {
      int t2 = __shfl_up(s, off);
      if (lane >= off) s += t2;
    }
    if (lane == 63) wpart[j & 1][wv] = s;
    __syncthreads();
    int wbase = 0, total = 0;
#pragma unroll
    for (int k = 0; k < 16; ++k) {  // LDS broadcast reads (no conflict)
      int w = wpart[j & 1][k];
      total += w;
      if (k < wv) wbase += w;
    }
    if (idx < N_NODES) {
      int p = carry + wbase + (s - v);
      rowstart[idx] = p;            // coalesced store
      cursor[idx]   = p;
    }
    carry += total;
  }
  if (tid == 0) rowstart[N_NODES] = carry;
  if (tid < 256) {
    int a = 0;
#pragma unroll
    for (int k = 0; k < 8; ++k) a += hist8[k][tid];
    hist[tid] = a;
  }
  __syncthreads();
  if (tid == 0) {
    int b = 0;                      // descending exclusive bucket scan
    for (int d = 255; d >= 0; --d) { int h = hist[d]; hist[d] = b; b += h; }
  }
  __syncthreads();
  if (tid < 256) bcur_g[tid] = hist[tid];
}

// ---------------- edge scatter + two-level perm placement ----------------
#define SCAT_EB ((N_EDGES + 255) / 256)   // 938
#define SCAT_NB ((N_NODES + 255) / 256)   // 118
__global__ __launch_bounds__(256) void k_scatter(
    const int* __restrict__ src, const int* __restrict__ dst,
    const int* __restrict__ etype, int* __restrict__ cursor,
    int* __restrict__ packed, const int* __restrict__ deg,
    int* __restrict__ bcur_g, int* __restrict__ perm) {
  int bid = blockIdx.x;
  int t = threadIdx.x;
  if (bid < SCAT_EB) {
    int e = bid * 256 + t;
    if (e < N_EDGES) {
      int p = atomicAdd(&cursor[dst[e]], 1);
      packed[p] = src[e] * NETYPES + etype[e];
    }
  } else {
    __shared__ int hist[256], lbase[256], lcur[256];
    hist[t] = 0;
    lcur[t] = 0;
    __syncthreads();
    int i = (bid - SCAT_EB) * 256 + t;
    int d = 0;
    bool valid = (i < N_NODES);
    if (valid) {
      d = deg[i]; if (d > 255) d = 255;
      atomicAdd(&hist[d], 1);
    }
    __syncthreads();
    int h = hist[t];
    if (h > 0) lbase[t] = atomicAdd(&bcur_g[t], h);
    __syncthreads();
    if (valid) {
      int r = atomicAdd(&lcur[d], 1);
      perm[lbase[d] + r] = i;
    }
  }
}

// ---------------- split-bf16 MFMA GEMM, 2-term (Ahi*Bhi + Alo*Bhi) ----------
__global__ __launch_bounds__(256, 5) void k_gemm_mfma(
    const unsigned short* __restrict__ Ahi, const unsigned short* __restrict__ Alo,
    const unsigned short* __restrict__ Bhi,
    const float* __restrict__ bcat, float* __restrict__ qbuf,
    unsigned short* __restrict__ kv) {
  __shared__ unsigned short smem[2 * 8192];

  int tid = threadIdx.x;
  int lane = tid & 63, wave = tid >> 6;
  int bx = blockIdx.x;
  int xcd = bx & 7, slot = bx >> 3;
  int rt = xcd + (slot / 6) * 8;
  if (rt >= 469) return;
  int row0 = rt * 64;
  int n0 = (slot % 6) * 128;
  int wm = (wave >> 1) * 32, wn = (wave & 1) * 64;
  int quad = lane >> 4, l16 = lane & 15;
  int lrow = lane >> 2;
  int chSw = (lane & 3) ^ ((lane >> 3) & 3);
  int rdSw = (quad ^ ((l16 >> 1) & 3)) * 8;

  f32x4 acc[2][4];
#pragma unroll
  for (int i = 0; i < 2; ++i)
#pragma unroll
    for (int j = 0; j < 4; ++j) acc[i][j] = (f32x4)(0.f);

  auto STAGE = [&](int k0, int b) {
    unsigned short* s = smem + b * 8192;
    int garA = row0 + wave * 16 + lrow; if (garA >= N_NODES) garA = N_NODES - 1;
    size_t acol = (size_t)garA * 256 + k0 + chSw * 8;
    async_g2l(Ahi + acol, s + wave * 512);
    async_g2l(Alo + acol, s + 2048 + wave * 512);
#pragma unroll
    for (int r = 0; r < 2; ++r) {
      int brow = r * 64 + wave * 16 + lrow;
      size_t boff = (size_t)(n0 + brow) * 256 + k0 + chSw * 8;
      async_g2l(Bhi + boff, s + 4096 + r * 2048 + wave * 512);
    }
  };

  STAGE(0, 0);
#pragma unroll
  for (int k = 0; k < 8; ++k) {
    int cur = k & 1;
    if (k < 7) {
      STAGE((k + 1) * 32, cur ^ 1);
      asm volatile("s_waitcnt vmcnt(4)" ::: "memory");
    } else {
      asm volatile("s_waitcnt vmcnt(0)" ::: "memory");
    }
    __builtin_amdgcn_s_barrier();

    const unsigned short* sAhi = smem + cur * 8192;
    const unsigned short* sAlo = sAhi + 2048;
    const unsigned short* sB   = sAhi + 4096;
    short8 ah[2], al[2], bh[4];
#pragma unroll
    for (int i = 0; i < 2; ++i) {
      int off = (wm + i * 16 + l16) * 32 + rdSw;
      ah[i] = *(const short8*)(sAhi + off);
      al[i] = *(const short8*)(sAlo + off);
    }
#pragma unroll
    for (int j = 0; j < 4; ++j) {
      int off = (wn + j * 16 + l16) * 32 + rdSw;
      bh[j] = *(const short8*)(sB + off);
    }
#pragma unroll
    for (int i = 0; i < 2; ++i)
#pragma unroll
      for (int j = 0; j < 4; ++j) {
        acc[i][j] = __builtin_amdgcn_mfma_f32_16x16x32_bf16(ah[i], bh[j], acc[i][j], 0, 0, 0);
        acc[i][j] = __builtin_amdgcn_mfma_f32_16x16x32_bf16(al[i], bh[j], acc[i][j], 0, 0, 0);
      }
    __builtin_amdgcn_s_barrier();
  }

  float bj[4];
#pragma unroll
  for (int j = 0; j < 4; ++j) bj[j] = bcat[n0 + wn + j * 16 + l16];
  bool isq = (n0 < 256);
  int cb = n0 - 256;
  int isV = cb >> 8;
  int cc0 = (cb & 255) + wn + l16;
#pragma unroll
  for (int i = 0; i < 2; ++i) {
    int rowb = row0 + wm + i * 16 + quad * 4;
#pragma unroll
    for (int r = 0; r < 4; ++r) {
      int grow = rowb + r;
      if (grow < N_NODES) {
        if (isq) {
          float* cp = qbuf + (size_t)grow * 256 + n0 + wn + l16;
#pragma unroll
          for (int j = 0; j < 4; ++j) cp[j * 16] = acc[i][j][r] + bj[j];
        } else {
          unsigned short* rowp = kv + (size_t)grow * 512 + isV * 4;
#pragma unroll
          for (int j = 0; j < 4; ++j) {
            int c = cc0 + j * 16;
            rowp[((c >> 2) << 3) + (c & 3)] = f2bf(acc[i][j][r] + bj[j]);
          }
        }
      }
    }
  }
}

// ---------------- per-dst-node edge attention (degree-sorted via perm) ----------
__global__ __launch_bounds__(256) void k_attn(
    const float* __restrict__ qbuf, const unsigned short* __restrict__ kv,
    const int* __restrict__ rowstart, const int* __restrict__ deg,
    const int* __restrict__ packed,
    const int* __restrict__ perm, const float* __restrict__ Eemb_l,
    unsigned short* __restrict__ xhi, unsigned short* __restrict__ xlo) {
  __shared__ float ete_s[NETYPES * 256];
  int t = threadIdx.x;
#pragma unroll
  for (int i = 0; i < NETYPES; ++i) ete_s[i * 256 + t] = Eemb_l[i * 256 + t];
  __syncthreads();
  int lane = t & 63;
  int n = perm[blockIdx.x * 4 + (t >> 6)];
  float4 q4 = ((const float4*)(qbuf + (size_t)n * 256))[lane];
  int rs = rowstart[n], re = rs + deg[n];   // rowstart no longer monotone
  float l1 = 0.f, ax1 = 0.f, ay1 = 0.f, az1 = 0.f, aw1 = 0.f;
  float l2 = 0.f, ax2 = 0.f, ay2 = 0.f, az2 = 0.f, aw2 = 0.f;
  int i = rs;
  for (; i + 2 <= re; i += 2) {
    int pkA = packed[i], pkB = packed[i + 1];
    ushort8 cA = ((const ushort8*)(kv + (size_t)(pkA >> 3) * 512))[lane];
    ushort8 cB = ((const ushort8*)(kv + (size_t)(pkB >> 3) * 512))[lane];
    float4 eA = ((const float4*)(ete_s + (pkA & 7) * 256))[lane];
    float4 eB = ((const float4*)(ete_s + (pkB & 7) * 256))[lane];
    float pA = (bf2f(cA[0]) + eA.x) * q4.x + (bf2f(cA[1]) + eA.y) * q4.y +
               (bf2f(cA[2]) + eA.z) * q4.z + (bf2f(cA[3]) + eA.w) * q4.w;
    float pB = (bf2f(cB[0]) + eB.x) * q4.x + (bf2f(cB[1]) + eB.y) * q4.y +
               (bf2f(cB[2]) + eB.z) * q4.z + (bf2f(cB[3]) + eB.w) * q4.w;
    pA = dpp_red_add(pA);
    pB = dpp_red_add(pB);
    float e1 = __expf(pA * 0.125f);
    float e2 = __expf(pB * 0.125f);
    l1 += e1; l2 += e2;
    ax1 = fmaf(e1, bf2f(cA[4]) + eA.x, ax1);
    ay1 = fmaf(e1, bf2f(cA[5]) + eA.y, ay1);
    az1 = fmaf(e1, bf2f(cA[6]) + eA.z, az1);
    aw1 = fmaf(e1, bf2f(cA[7]) + eA.w, aw1);
    ax2 = fmaf(e2, bf2f(cB[4]) + eB.x, ax2);
    ay2 = fmaf(e2, bf2f(cB[5]) + eB.y, ay2);
    az2 = fmaf(e2, bf2f(cB[6]) + eB.z, az2);
    aw2 = fmaf(e2, bf2f(cB[7]) + eB.w, aw2);
  }
  if (i < re) {
    int pk = packed[i];
    ushort8 c = ((const ushort8*)(kv + (size_t)(pk >> 3) * 512))[lane];
    float4 e4 = ((const float4*)(ete_s + (pk & 7) * 256))[lane];
    float p = (bf2f(c[0]) + e4.x) * q4.x + (bf2f(c[1]) + e4.y) * q4.y +
              (bf2f(c[2]) + e4.z) * q4.z + (bf2f(c[3]) + e4.w) * q4.w;
    p = dpp_red_add(p);
    float e1 = __expf(p * 0.125f);
    l1 += e1;
    ax1 = fmaf(e1, bf2f(c[4]) + e4.x, ax1);
    ay1 = fmaf(e1, bf2f(c[5]) + e4.y, ay1);
    az1 = fmaf(e1, bf2f(c[6]) + e4.z, az1);
    aw1 = fmaf(e1, bf2f(c[7]) + e4.w, aw1);
  }
  float l = l1 + l2;
  float inv = 1.f / (l + 1e-16f);
  float4 o;
  o.x = (ax1 + ax2) * inv; o.y = (ay1 + ay2) * inv;
  o.z = (az1 + az2) * inv; o.w = (aw1 + aw2) * inv;
  o.x = o.x > 0.f ? o.x : expm1f(o.x);
  o.y = o.y > 0.f ? o.y : expm1f(o.y);
  o.z = o.z > 0.f ? o.z : expm1f(o.z);
  o.w = o.w > 0.f ? o.w : expm1f(o.w);
  unsigned short h0 = f2bf(o.x), h1 = f2bf(o.y), h2 = f2bf(o.z), h3 = f2bf(o.w);
  ushort4 hv, lv;
  hv.x = h0; hv.y = h1; hv.z = h2; hv.w = h3;
  lv.x = f2bf(o.x - bf2f(h0)); lv.y = f2bf(o.y - bf2f(h1));
  lv.z = f2bf(o.z - bf2f(h2)); lv.w = f2bf(o.w - bf2f(h3));
  size_t base_o = (size_t)n * 256 + lane * 4;
  *(ushort4*)(xhi + base_o) = hv;
  *(ushort4*)(xlo + base_o) = lv;
}

// ---------------- parallel mean pool, stage 1 ----------------
__global__ __launch_bounds__(256) void k_pool_partial(
    const unsigned short* __restrict__ xhi, const unsigned short* __restrict__ xlo,
    const int* __restrict__ batch, float* __restrict__ gacc) {
  int t = threadIdx.x;
  int base = blockIdx.x * 128;
  int end = base + 128; if (end > N_NODES) end = N_NODES;
  __shared__ int bsh[128];
  if (t < 128 && base + t < N_NODES) bsh[t] = batch[base + t];
  __syncthreads();
  float acc = 0.f;
  int cur = bsh[0];
  for (int n = base; n < end; ++n) {
    int g = bsh[n - base];
    if (g != cur) {
      atomicAdd(&gacc[cur * 256 + t], acc);
      acc = 0.f; cur = g;
    }
    size_t idx = (size_t)n * 256 + t;
    acc += bf2f(xhi[idx]) + bf2f(xlo[idx]);
  }
  atomicAdd(&gacc[cur * 256 + t], acc);
}

// ---------------- GRU (h0=0) + FC ----------------
__device__ inline int lower_bound_dev(const int* a, int n, int val) {
  int lo = 0, hi = n;
  while (lo < hi) {
    int mid = (lo + hi) >> 1;
    if (a[mid] < val) lo = mid + 1; else hi = mid;
  }
  return lo;
}

__global__ __launch_bounds__(256) void k_gru_fc(
    const float* __restrict__ gacc, const int* __restrict__ batch,
    const float* __restrict__ W_ih, const float* __restrict__ b_ih,
    const float* __restrict__ b_hh, const float* __restrict__ W_fc,
    const float* __restrict__ b_fc, float* __restrict__ out) {
  __shared__ float gv[256];
  __shared__ float gates[192];
  __shared__ float h[64];
  int gr = blockIdx.x, t = threadIdx.x;
  int s0 = lower_bound_dev(batch, N_NODES, gr);
  int e0 = lower_bound_dev(batch, N_NODES, gr + 1);
  float c = (e0 > s0) ? (float)(e0 - s0) : 1.f;
  gv[t] = gacc[gr * 256 + t] / c;
  __syncthreads();
  if (t < 192) {
    const float* wr = W_ih + t * 256;
    float s = b_ih[t];
    for (int k = 0; k < 256; ++k) s = fmaf(gv[k], wr[k], s);
    gates[t] = s;
  }
  __syncthreads();
  if (t < 64) {
    float r  = 1.f / (1.f + expf(-(gates[t] + b_hh[t])));
    float z  = 1.f / (1.f + expf(-(gates[64 + t] + b_hh[64 + t])));
    float nn = tanhf(gates[128 + t] + r * b_hh[128 + t]);
    h[t] = (1.f - z) * nn;
  }
  __syncthreads();
  if (t < 2) {
    const float* wr = W_fc + t * 64;
    float s = b_fc[t];
    for (int k = 0; k < 64; ++k) s = fmaf(h[k], wr[k], s);
    out[gr * 2 + t] = s;
  }
}

extern "C" void kernel_launch(void* const* d_in, const int* in_sizes, int n_in,
                              void* d_out, int out_size, void* d_ws, size_t ws_size,
                              hipStream_t stream) {
  const float* x     = (const float*)d_in[0];
  const int* edge_index = (const int*)d_in[1];
  const int* batch   = (const int*)d_in[2];
  const int* etype   = (const int*)d_in[3];
  const float* Wq    = (const float*)d_in[4];
  const float* bq    = (const float*)d_in[5];
  const float* Wk    = (const float*)d_in[6];
  const float* bk    = (const float*)d_in[7];
  const float* Wv    = (const float*)d_in[8];
  const float* bv    = (const float*)d_in[9];
  const float* Eemb  = (const float*)d_in[10];
  const float* W_ih  = (const float*)d_in[11];
  const float* b_ih  = (const float*)d_in[12];
  const float* b_hh  = (const float*)d_in[14];
  const float* W_fc  = (const float*)d_in[15];
  const float* b_fc  = (const float*)d_in[16];
  float* out = (float*)d_out;

  const int* src = edge_index;
  const int* dst = edge_index + N_EDGES;

  float* qbuf  = (float*)d_ws;                             // N*256 f32
  float* gacc  = qbuf + (size_t)N_NODES * 256;             // 64*256
  float* bcat  = gacc + NGRAPHS * 256;                     // 3*768
  unsigned short* kv   = (unsigned short*)(bcat + NLAYERS * 768);  // N*512 bf16
  unsigned short* xhi  = kv + (size_t)N_NODES * 512;       // N*256
  unsigned short* xlo  = xhi + (size_t)N_NODES * 256;
  unsigned short* wthi = xlo + (size_t)N_NODES * 256;      // 3*768*256
  int* deg      = (int*)(wthi + (size_t)NLAYERS * 768 * 256);
  int* rowstart = deg + N_NODES;
  int* cursor   = rowstart + N_NODES + 1;
  int* packed   = cursor + N_NODES;
  int* perm     = packed + N_EDGES;
  int* bcur_g   = perm + N_NODES;

  hipMemsetAsync(deg, 0, N_NODES * sizeof(int), stream);
  k_prep<<<PREP_BLOCKS, 256, 0, stream>>>(dst, deg, x, xhi, xlo,
                                          Wq, Wk, Wv, wthi, bq, bk, bv, bcat, gacc);
  k_scan_sort<<<1, 1024, 0, stream>>>(deg, rowstart, cursor, bcur_g);
  k_scatter<<<SCAT_EB + SCAT_NB, 256, 0, stream>>>(src, dst, etype, cursor, packed,
                                                   deg, bcur_g, perm);

  for (int l = 0; l < NLAYERS; ++l) {
    k_gemm_mfma<<<59 * 8 * 6, 256, 0, stream>>>(
        xhi, xlo, wthi + (size_t)l * 768 * 256,
        bcat + l * 768, qbuf, kv);
    k_attn<<<N_NODES / 4, 256, 0, stream>>>(qbuf, kv, rowstart, deg, packed, perm,
                                            Eemb + (size_t)l * NETYPES * 256, xhi, xlo);
  }
  k_pool_partial<<<(N_NODES + 127) / 128, 256, 0, stream>>>(xhi, xlo, batch, gacc);
  k_gru_fc<<<NGRAPHS, 256, 0, stream>>>(gacc, batch, W_ih, b_ih, b_hh, W_fc, b_fc, out);
}

// Round 12
// 412.232 us; speedup vs baseline: 1.3252x; 1.0826x over previous
//
#include <hip/hip_runtime.h>
#include <math.h>

#define N_NODES 30000
#define N_EDGES 240000
#define DMODEL 256
#define NETYPES 8
#define NGRAPHS 64
#define NLAYERS 3

typedef __attribute__((ext_vector_type(8))) short short8;
typedef __attribute__((ext_vector_type(8))) unsigned short ushort8;
typedef __attribute__((ext_vector_type(4))) float f32x4;

// ---- bf16 split helpers (round-to-nearest-even) ----
__device__ __forceinline__ unsigned short f2bf(float f) {
  union { float f; unsigned u; } v; v.f = f;
  unsigned r = v.u + 0x7FFF + ((v.u >> 16) & 1);
  return (unsigned short)(r >> 16);
}
__device__ __forceinline__ float bf2f(unsigned short h) {
  union { unsigned u; float f; } v; v.u = ((unsigned)h) << 16;
  return v.f;
}

__device__ __forceinline__ void async_g2l(const unsigned short* g, unsigned short* l) {
  __builtin_amdgcn_global_load_lds(
      (const __attribute__((address_space(1))) void*)g,
      (__attribute__((address_space(3))) void*)l, 16, 0, 0);
}

// 16-lane (intra-head) sum via DPP.
__device__ __forceinline__ float dpp_red_add(float x) {
  int v = __float_as_int(x);
  int t;
  t = __builtin_amdgcn_update_dpp(0, v, 0xB1, 0xF, 0xF, true);   // quad_perm [1,0,3,2]
  v = __float_as_int(__int_as_float(v) + __int_as_float(t));
  t = __builtin_amdgcn_update_dpp(0, v, 0x4E, 0xF, 0xF, true);   // quad_perm [2,3,0,1]
  v = __float_as_int(__int_as_float(v) + __int_as_float(t));
  t = __builtin_amdgcn_update_dpp(0, v, 0x141, 0xF, 0xF, true);  // row_half_mirror (^7)
  v = __float_as_int(__int_as_float(v) + __int_as_float(t));
  t = __builtin_amdgcn_update_dpp(0, v, 0x140, 0xF, 0xF, true);  // row_mirror (^15)
  v = __float_as_int(__int_as_float(v) + __int_as_float(t));
  return __int_as_float(v);
}

// ---------------- fused prologue: count_deg | cvt_x | cvt_w | cvt_b | zero gacc ----
#define PREP_CNT 938
#define PREP_CVTX 3750
#define PREP_CVTW 576
#define PREP_CVTB 9
#define PREP_GACC 64
#define B_CVTX (PREP_CNT)
#define B_CVTW (B_CVTX + PREP_CVTX)
#define B_CVTB (B_CVTW + PREP_CVTW)
#define B_GACC (B_CVTB + PREP_CVTB)
#define PREP_BLOCKS (B_GACC + PREP_GACC)

__global__ __launch_bounds__(256) void k_prep(
    const int* __restrict__ dst, int* __restrict__ deg,
    const float* __restrict__ x, unsigned short* __restrict__ xhi,
    unsigned short* __restrict__ xlo,
    const float* __restrict__ Wq, const float* __restrict__ Wk,
    const float* __restrict__ Wv, unsigned short* __restrict__ wthi,
    const float* __restrict__ bq, const float* __restrict__ bk,
    const float* __restrict__ bv, float* __restrict__ bcat,
    float* __restrict__ gacc) {
  __shared__ float tile[32][33];
  int bid = blockIdx.x, t = threadIdx.x;
  if (bid < PREP_CNT) {
    int e = bid * 256 + t;
    if (e < N_EDGES) atomicAdd(&deg[dst[e]], 1);
  } else if (bid < B_CVTW) {
    size_t i0 = ((size_t)(bid - B_CVTX) * 256 + t) * 8;
#pragma unroll
    for (int h = 0; h < 2; ++h) {
      float4 v4 = *(const float4*)(x + i0 + h * 4);
      ushort4 hv, lv;
      hv.x = f2bf(v4.x); lv.x = f2bf(v4.x - bf2f(hv.x));
      hv.y = f2bf(v4.y); lv.y = f2bf(v4.y - bf2f(hv.y));
      hv.z = f2bf(v4.z); lv.z = f2bf(v4.z - bf2f(hv.z));
      hv.w = f2bf(v4.w); lv.w = f2bf(v4.w - bf2f(hv.w));
      *(ushort4*)(xhi + i0 + h * 4) = hv;
      *(ushort4*)(xlo + i0 + h * 4) = lv;
    }
  } else if (bid < B_CVTB) {
    int rel = bid - B_CVTW;
    int k0 = (rel & 7) * 32;
    int n0g = ((rel >> 3) % 24) * 32;
    int l = rel / 192;
    int which = n0g >> 8;
    int col0 = n0g & 255;
    const float* W = (which == 0) ? Wq : ((which == 1) ? Wk : Wv);
    int c = t & 31, r = t >> 5;
#pragma unroll
    for (int rr = 0; rr < 4; ++rr) {
      int kk = r + rr * 8;
      tile[kk][c] = W[(size_t)l * 65536 + (size_t)(k0 + kk) * 256 + col0 + c];
    }
    __syncthreads();
    int kk = t & 31, nn0 = t >> 5;
#pragma unroll
    for (int rr = 0; rr < 4; ++rr) {
      int nn = nn0 + rr * 8;
      wthi[((size_t)l * 768 + n0g + nn) * 256 + k0 + kk] = f2bf(tile[kk][nn]);
    }
  } else if (bid < B_GACC) {
    int idx = (bid - B_CVTB) * 256 + t;
    if (idx < NLAYERS * 768) {
      int n = idx % 768, l = idx / 768;
      int which = n >> 8, col = n & 255;
      const float* b = (which == 0) ? bq : ((which == 1) ? bk : bv);
      bcat[idx] = b[l * 256 + col];
    }
  } else {
    int idx = (bid - B_GACC) * 256 + t;
    gacc[idx] = 0.f;
  }
}

// ---------------- coalesced scan (transposed order) + histogram ----------------
__global__ __launch_bounds__(1024) void k_scan_sort(
    const int* __restrict__ deg, int* __restrict__ rowstart,
    int* __restrict__ cursor, int* __restrict__ bcur_g) {
  const int R = 30;                 // 30*1024 = 30720 >= N_NODES
  __shared__ int hist8[8][256];
  __shared__ int hist[256];
  __shared__ int wpart[2][16];
  int tid = threadIdx.x;
  int lane = tid & 63, wv = tid >> 6;
  int sub = tid >> 7;
  for (int k = tid; k < 8 * 256; k += 1024) ((int*)hist8)[k] = 0;
  __syncthreads();
  int carry = 0;
  for (int j = 0; j < R; ++j) {
    int idx = j * 1024 + tid;       // coalesced: lane-contiguous
    int v = (idx < N_NODES) ? deg[idx] : 0;
    if (idx < N_NODES) {
      int d = v > 255 ? 255 : v;
      atomicAdd(&hist8[sub][d], 1);
    }
    int s = v;                      // wave-inclusive scan
#pragma unroll
    for (int off = 1; off < 64; off <<= 1) {
      int t2 = __shfl_up(s, off);
      if (lane >= off) s += t2;
    }
    if (lane == 63) wpart[j & 1][wv] = s;
    __syncthreads();
    int wbase = 0, total = 0;
#pragma unroll
    for (int k = 0; k < 16; ++k) {
      int w = wpart[j & 1][k];
      total += w;
      if (k < wv) wbase += w;
    }
    if (idx < N_NODES) {
      int p = carry + wbase + (s - v);
      rowstart[idx] = p;
      cursor[idx]   = p;
    }
    carry += total;
  }
  if (tid == 0) rowstart[N_NODES] = carry;
  if (tid < 256) {
    int a = 0;
#pragma unroll
    for (int k = 0; k < 8; ++k) a += hist8[k][tid];
    hist[tid] = a;
  }
  __syncthreads();
  if (tid == 0) {
    int b = 0;                      // descending exclusive bucket scan
    for (int d = 255; d >= 0; --d) { int h = hist[d]; hist[d] = b; b += h; }
  }
  __syncthreads();
  if (tid < 256) bcur_g[tid] = hist[tid];
}

// ---------------- edge scatter + two-level perm placement ----------------
#define SCAT_EB ((N_EDGES + 255) / 256)   // 938
#define SCAT_NB ((N_NODES + 255) / 256)   // 118
__global__ __launch_bounds__(256) void k_scatter(
    const int* __restrict__ src, const int* __restrict__ dst,
    const int* __restrict__ etype, int* __restrict__ cursor,
    int* __restrict__ packed, const int* __restrict__ deg,
    int* __restrict__ bcur_g, int* __restrict__ perm) {
  int bid = blockIdx.x;
  int t = threadIdx.x;
  if (bid < SCAT_EB) {
    int e = bid * 256 + t;
    if (e < N_EDGES) {
      int p = atomicAdd(&cursor[dst[e]], 1);
      packed[p] = src[e] * NETYPES + etype[e];
    }
  } else {
    __shared__ int hist[256], lbase[256], lcur[256];
    hist[t] = 0;
    lcur[t] = 0;
    __syncthreads();
    int i = (bid - SCAT_EB) * 256 + t;
    int d = 0;
    bool valid = (i < N_NODES);
    if (valid) {
      d = deg[i]; if (d > 255) d = 255;
      atomicAdd(&hist[d], 1);
    }
    __syncthreads();
    int h = hist[t];
    if (h > 0) lbase[t] = atomicAdd(&bcur_g[t], h);
    __syncthreads();
    if (valid) {
      int r = atomicAdd(&lcur[d], 1);
      perm[lbase[d] + r] = i;
    }
  }
}

// ---------------- split-bf16 MFMA GEMM, 2-term (Ahi*Bhi + Alo*Bhi) ----------
// v7: TRIPLE-buffered LDS -> ONE s_barrier per K-step (the dbuf's trailing
// barrier was protecting buffer reuse at distance 1; at distance 2 the
// previous iteration's barrier protects transitively). 48KB LDS, 3 blocks/CU.
__global__ __launch_bounds__(256, 3) void k_gemm_mfma(
    const unsigned short* __restrict__ Ahi, const unsigned short* __restrict__ Alo,
    const unsigned short* __restrict__ Bhi,
    const float* __restrict__ bcat, float* __restrict__ qbuf,
    unsigned short* __restrict__ kv) {
  __shared__ unsigned short smem[3 * 8192];

  int tid = threadIdx.x;
  int lane = tid & 63, wave = tid >> 6;
  int bx = blockIdx.x;
  int xcd = bx & 7, slot = bx >> 3;
  int rt = xcd + (slot / 6) * 8;
  if (rt >= 469) return;
  int row0 = rt * 64;
  int n0 = (slot % 6) * 128;
  int wm = (wave >> 1) * 32, wn = (wave & 1) * 64;
  int quad = lane >> 4, l16 = lane & 15;
  int lrow = lane >> 2;
  int chSw = (lane & 3) ^ ((lane >> 3) & 3);
  int rdSw = (quad ^ ((l16 >> 1) & 3)) * 8;

  f32x4 acc[2][4];
#pragma unroll
  for (int i = 0; i < 2; ++i)
#pragma unroll
    for (int j = 0; j < 4; ++j) acc[i][j] = (f32x4)(0.f);

  auto STAGE = [&](int k0, int b) {
    unsigned short* s = smem + b * 8192;
    int garA = row0 + wave * 16 + lrow; if (garA >= N_NODES) garA = N_NODES - 1;
    size_t acol = (size_t)garA * 256 + k0 + chSw * 8;
    async_g2l(Ahi + acol, s + wave * 512);
    async_g2l(Alo + acol, s + 2048 + wave * 512);
#pragma unroll
    for (int r = 0; r < 2; ++r) {
      int brow = r * 64 + wave * 16 + lrow;
      size_t boff = (size_t)(n0 + brow) * 256 + k0 + chSw * 8;
      async_g2l(Bhi + boff, s + 4096 + r * 2048 + wave * 512);
    }
  };

  STAGE(0, 0);
#pragma unroll
  for (int k = 0; k < 8; ++k) {
    int cur = k % 3;
    if (k < 7) {
      STAGE((k + 1) * 32, (k + 1) % 3);
      asm volatile("s_waitcnt vmcnt(4)" ::: "memory");
    } else {
      asm volatile("s_waitcnt vmcnt(0)" ::: "memory");
    }
    __builtin_amdgcn_s_barrier();   // all waves' tile-k loads certified done

    const unsigned short* sAhi = smem + cur * 8192;
    const unsigned short* sAlo = sAhi + 2048;
    const unsigned short* sB   = sAhi + 4096;
    short8 ah[2], al[2], bh[4];
#pragma unroll
    for (int i = 0; i < 2; ++i) {
      int off = (wm + i * 16 + l16) * 32 + rdSw;
      ah[i] = *(const short8*)(sAhi + off);
      al[i] = *(const short8*)(sAlo + off);
    }
#pragma unroll
    for (int j = 0; j < 4; ++j) {
      int off = (wn + j * 16 + l16) * 32 + rdSw;
      bh[j] = *(const short8*)(sB + off);
    }
#pragma unroll
    for (int i = 0; i < 2; ++i)
#pragma unroll
      for (int j = 0; j < 4; ++j) {
        acc[i][j] = __builtin_amdgcn_mfma_f32_16x16x32_bf16(ah[i], bh[j], acc[i][j], 0, 0, 0);
        acc[i][j] = __builtin_amdgcn_mfma_f32_16x16x32_bf16(al[i], bh[j], acc[i][j], 0, 0, 0);
      }
    // no trailing barrier: next STAGE targets buf (k+2)%3, last read at k-1,
    // protected by the NEXT iteration's leading barrier transitively.
  }

  float bj[4];
#pragma unroll
  for (int j = 0; j < 4; ++j) bj[j] = bcat[n0 + wn + j * 16 + l16];
  bool isq = (n0 < 256);
  int cb = n0 - 256;
  int isV = cb >> 8;
  int cc0 = (cb & 255) + wn + l16;
#pragma unroll
  for (int i = 0; i < 2; ++i) {
    int rowb = row0 + wm + i * 16 + quad * 4;
#pragma unroll
    for (int r = 0; r < 4; ++r) {
      int grow = rowb + r;
      if (grow < N_NODES) {
        if (isq) {
          float* cp = qbuf + (size_t)grow * 256 + n0 + wn + l16;
#pragma unroll
          for (int j = 0; j < 4; ++j) cp[j * 16] = acc[i][j][r] + bj[j];
        } else {
          unsigned short* rowp = kv + (size_t)grow * 512 + isV * 4;
#pragma unroll
          for (int j = 0; j < 4; ++j) {
            int c = cc0 + j * 16;
            rowp[((c >> 2) << 3) + (c & 3)] = f2bf(acc[i][j][r] + bj[j]);
          }
        }
      }
    }
  }
}

// ---------------- per-dst-node edge attention (degree-sorted via perm) ----------
__global__ __launch_bounds__(256) void k_attn(
    const float* __restrict__ qbuf, const unsigned short* __restrict__ kv,
    const int* __restrict__ rowstart, const int* __restrict__ deg,
    const int* __restrict__ packed,
    const int* __restrict__ perm, const float* __restrict__ Eemb_l,
    unsigned short* __restrict__ xhi, unsigned short* __restrict__ xlo) {
  __shared__ float ete_s[NETYPES * 256];
  int t = threadIdx.x;
#pragma unroll
  for (int i = 0; i < NETYPES; ++i) ete_s[i * 256 + t] = Eemb_l[i * 256 + t];
  __syncthreads();
  int lane = t & 63;
  int n = perm[blockIdx.x * 4 + (t >> 6)];
  float4 q4 = ((const float4*)(qbuf + (size_t)n * 256))[lane];
  int rs = rowstart[n], re = rs + deg[n];
  float l1 = 0.f, ax1 = 0.f, ay1 = 0.f, az1 = 0.f, aw1 = 0.f;
  float l2 = 0.f, ax2 = 0.f, ay2 = 0.f, az2 = 0.f, aw2 = 0.f;
  int i = rs;
  for (; i + 2 <= re; i += 2) {
    int pkA = packed[i], pkB = packed[i + 1];
    ushort8 cA = ((const ushort8*)(kv + (size_t)(pkA >> 3) * 512))[lane];
    ushort8 cB = ((const ushort8*)(kv + (size_t)(pkB >> 3) * 512))[lane];
    float4 eA = ((const float4*)(ete_s + (pkA & 7) * 256))[lane];
    float4 eB = ((const float4*)(ete_s + (pkB & 7) * 256))[lane];
    float pA = (bf2f(cA[0]) + eA.x) * q4.x + (bf2f(cA[1]) + eA.y) * q4.y +
               (bf2f(cA[2]) + eA.z) * q4.z + (bf2f(cA[3]) + eA.w) * q4.w;
    float pB = (bf2f(cB[0]) + eB.x) * q4.x + (bf2f(cB[1]) + eB.y) * q4.y +
               (bf2f(cB[2]) + eB.z) * q4.z + (bf2f(cB[3]) + eB.w) * q4.w;
    pA = dpp_red_add(pA);
    pB = dpp_red_add(pB);
    float e1 = __expf(pA * 0.125f);
    float e2 = __expf(pB * 0.125f);
    l1 += e1; l2 += e2;
    ax1 = fmaf(e1, bf2f(cA[4]) + eA.x, ax1);
    ay1 = fmaf(e1, bf2f(cA[5]) + eA.y, ay1);
    az1 = fmaf(e1, bf2f(cA[6]) + eA.z, az1);
    aw1 = fmaf(e1, bf2f(cA[7]) + eA.w, aw1);
    ax2 = fmaf(e2, bf2f(cB[4]) + eB.x, ax2);
    ay2 = fmaf(e2, bf2f(cB[5]) + eB.y, ay2);
    az2 = fmaf(e2, bf2f(cB[6]) + eB.z, az2);
    aw2 = fmaf(e2, bf2f(cB[7]) + eB.w, aw2);
  }
  if (i < re) {
    int pk = packed[i];
    ushort8 c = ((const ushort8*)(kv + (size_t)(pk >> 3) * 512))[lane];
    float4 e4 = ((const float4*)(ete_s + (pk & 7) * 256))[lane];
    float p = (bf2f(c[0]) + e4.x) * q4.x + (bf2f(c[1]) + e4.y) * q4.y +
              (bf2f(c[2]) + e4.z) * q4.z + (bf2f(c[3]) + e4.w) * q4.w;
    p = dpp_red_add(p);
    float e1 = __expf(p * 0.125f);
    l1 += e1;
    ax1 = fmaf(e1, bf2f(c[4]) + e4.x, ax1);
    ay1 = fmaf(e1, bf2f(c[5]) + e4.y, ay1);
    az1 = fmaf(e1, bf2f(c[6]) + e4.z, az1);
    aw1 = fmaf(e1, bf2f(c[7]) + e4.w, aw1);
  }
  float l = l1 + l2;
  float inv = 1.f / (l + 1e-16f);
  float4 o;
  o.x = (ax1 + ax2) * inv; o.y = (ay1 + ay2) * inv;
  o.z = (az1 + az2) * inv; o.w = (aw1 + aw2) * inv;
  o.x = o.x > 0.f ? o.x : expm1f(o.x);
  o.y = o.y > 0.f ? o.y : expm1f(o.y);
  o.z = o.z > 0.f ? o.z : expm1f(o.z);
  o.w = o.w > 0.f ? o.w : expm1f(o.w);
  unsigned short h0 = f2bf(o.x), h1 = f2bf(o.y), h2 = f2bf(o.z), h3 = f2bf(o.w);
  ushort4 hv, lv;
  hv.x = h0; hv.y = h1; hv.z = h2; hv.w = h3;
  lv.x = f2bf(o.x - bf2f(h0)); lv.y = f2bf(o.y - bf2f(h1));
  lv.z = f2bf(o.z - bf2f(h2)); lv.w = f2bf(o.w - bf2f(h3));
  size_t base_o = (size_t)n * 256 + lane * 4;
  *(ushort4*)(xhi + base_o) = hv;
  *(ushort4*)(xlo + base_o) = lv;
}

// ---------------- parallel mean pool, stage 1 ----------------
// v2: 16 nodes/block (1875 blocks, ~7/CU) — the 128-node serial loop left
// <1 wave/SIMD and ~128 exposed load latencies per block.
#define POOL_NPB 16
#define POOL_BLOCKS ((N_NODES + POOL_NPB - 1) / POOL_NPB)
__global__ __launch_bounds__(256) void k_pool_partial(
    const unsigned short* __restrict__ xhi, const unsigned short* __restrict__ xlo,
    const int* __restrict__ batch, float* __restrict__ gacc) {
  int t = threadIdx.x;
  int base = blockIdx.x * POOL_NPB;
  int end = base + POOL_NPB; if (end > N_NODES) end = N_NODES;
  __shared__ int bsh[POOL_NPB];
  if (t < POOL_NPB && base + t < N_NODES) bsh[t] = batch[base + t];
  __syncthreads();
  float acc = 0.f;
  int cur = bsh[0];
  for (int n = base; n < end; ++n) {
    int g = bsh[n - base];
    if (g != cur) {
      atomicAdd(&gacc[cur * 256 + t], acc);
      acc = 0.f; cur = g;
    }
    size_t idx = (size_t)n * 256 + t;
    acc += bf2f(xhi[idx]) + bf2f(xlo[idx]);
  }
  atomicAdd(&gacc[cur * 256 + t], acc);
}

// ---------------- GRU (h0=0) + FC ----------------
__device__ inline int lower_bound_dev(const int* a, int n, int val) {
  int lo = 0, hi = n;
  while (lo < hi) {
    int mid = (lo + hi) >> 1;
    if (a[mid] < val) lo = mid + 1; else hi = mid;
  }
  return lo;
}

__global__ __launch_bounds__(256) void k_gru_fc(
    const float* __restrict__ gacc, const int* __restrict__ batch,
    const float* __restrict__ W_ih, const float* __restrict__ b_ih,
    const float* __restrict__ b_hh, const float* __restrict__ W_fc,
    const float* __restrict__ b_fc, float* __restrict__ out) {
  __shared__ float gv[256];
  __shared__ float gates[192];
  __shared__ float h[64];
  int gr = blockIdx.x, t = threadIdx.x;
  int s0 = lower_bound_dev(batch, N_NODES, gr);
  int e0 = lower_bound_dev(batch, N_NODES, gr + 1);
  float c = (e0 > s0) ? (float)(e0 - s0) : 1.f;
  gv[t] = gacc[gr * 256 + t] / c;
  __syncthreads();
  if (t < 192) {
    const float* wr = W_ih + t * 256;
    float s = b_ih[t];
    for (int k = 0; k < 256; ++k) s = fmaf(gv[k], wr[k], s);
    gates[t] = s;
  }
  __syncthreads();
  if (t < 64) {
    float r  = 1.f / (1.f + expf(-(gates[t] + b_hh[t])));
    float z  = 1.f / (1.f + expf(-(gates[64 + t] + b_hh[64 + t])));
    float nn = tanhf(gates[128 + t] + r * b_hh[128 + t]);
    h[t] = (1.f - z) * nn;
  }
  __syncthreads();
  if (t < 2) {
    const float* wr = W_fc + t * 64;
    float s = b_fc[t];
    for (int k = 0; k < 64; ++k) s = fmaf(h[k], wr[k], s);
    out[gr * 2 + t] = s;
  }
}

extern "C" void kernel_launch(void* const* d_in, const int* in_sizes, int n_in,
                              void* d_out, int out_size, void* d_ws, size_t ws_size,
                              hipStream_t stream) {
  const float* x     = (const float*)d_in[0];
  const int* edge_index = (const int*)d_in[1];
  const int* batch   = (const int*)d_in[2];
  const int* etype   = (const int*)d_in[3];
  const float* Wq    = (const float*)d_in[4];
  const float* bq    = (const float*)d_in[5];
  const float* Wk    = (const float*)d_in[6];
  const float* bk    = (const float*)d_in[7];
  const float* Wv    = (const float*)d_in[8];
  const float* bv    = (const float*)d_in[9];
  const float* Eemb  = (const float*)d_in[10];
  const float* W_ih  = (const float*)d_in[11];
  const float* b_ih  = (const float*)d_in[12];
  const float* b_hh  = (const float*)d_in[14];
  const float* W_fc  = (const float*)d_in[15];
  const float* b_fc  = (const float*)d_in[16];
  float* out = (float*)d_out;

  const int* src = edge_index;
  const int* dst = edge_index + N_EDGES;

  float* qbuf  = (float*)d_ws;                             // N*256 f32
  float* gacc  = qbuf + (size_t)N_NODES * 256;             // 64*256
  float* bcat  = gacc + NGRAPHS * 256;                     // 3*768
  unsigned short* kv   = (unsigned short*)(bcat + NLAYERS * 768);  // N*512 bf16
  unsigned short* xhi  = kv + (size_t)N_NODES * 512;       // N*256
  unsigned short* xlo  = xhi + (size_t)N_NODES * 256;
  unsigned short* wthi = xlo + (size_t)N_NODES * 256;      // 3*768*256
  int* deg      = (int*)(wthi + (size_t)NLAYERS * 768 * 256);
  int* rowstart = deg + N_NODES;
  int* cursor   = rowstart + N_NODES + 1;
  int* packed   = cursor + N_NODES;
  int* perm     = packed + N_EDGES;
  int* bcur_g   = perm + N_NODES;

  hipMemsetAsync(deg, 0, N_NODES * sizeof(int), stream);
  k_prep<<<PREP_BLOCKS, 256, 0, stream>>>(dst, deg, x, xhi, xlo,
                                          Wq, Wk, Wv, wthi, bq, bk, bv, bcat, gacc);
  k_scan_sort<<<1, 1024, 0, stream>>>(deg, rowstart, cursor, bcur_g);
  k_scatter<<<SCAT_EB + SCAT_NB, 256, 0, stream>>>(src, dst, etype, cursor, packed,
                                                   deg, bcur_g, perm);

  for (int l = 0; l < NLAYERS; ++l) {
    k_gemm_mfma<<<59 * 8 * 6, 256, 0, stream>>>(
        xhi, xlo, wthi + (size_t)l * 768 * 256,
        bcat + l * 768, qbuf, kv);
    k_attn<<<N_NODES / 4, 256, 0, stream>>>(qbuf, kv, rowstart, deg, packed, perm,
                                            Eemb + (size_t)l * NETYPES * 256, xhi, xlo);
  }
  k_pool_partial<<<POOL_BLOCKS, 256, 0, stream>>>(xhi, xlo, batch, gacc);
  k_gru_fc<<<NGRAPHS, 256, 0, stream>>>(gacc, batch, W_ih, b_ih, b_hh, W_fc, b_fc, out);
}

// Round 13
// 409.258 us; speedup vs baseline: 1.3348x; 1.0073x over previous
//
#include <hip/hip_runtime.h>
#include <math.h>

#define N_NODES 30000
#define N_EDGES 240000
#define DMODEL 256
#define NETYPES 8
#define NGRAPHS 64
#define NLAYERS 3

typedef __attribute__((ext_vector_type(8))) short short8;
typedef __attribute__((ext_vector_type(8))) unsigned short ushort8;
typedef __attribute__((ext_vector_type(4))) float f32x4;

// ---- bf16 split helpers (round-to-nearest-even) ----
__device__ __forceinline__ unsigned short f2bf(float f) {
  union { float f; unsigned u; } v; v.f = f;
  unsigned r = v.u + 0x7FFF + ((v.u >> 16) & 1);
  return (unsigned short)(r >> 16);
}
__device__ __forceinline__ float bf2f(unsigned short h) {
  union { unsigned u; float f; } v; v.u = ((unsigned)h) << 16;
  return v.f;
}

__device__ __forceinline__ void async_g2l(const unsigned short* g, unsigned short* l) {
  __builtin_amdgcn_global_load_lds(
      (const __attribute__((address_space(1))) void*)g,
      (__attribute__((address_space(3))) void*)l, 16, 0, 0);
}

// 16-lane (intra-head) sum via DPP.
__device__ __forceinline__ float dpp_red_add(float x) {
  int v = __float_as_int(x);
  int t;
  t = __builtin_amdgcn_update_dpp(0, v, 0xB1, 0xF, 0xF, true);   // quad_perm [1,0,3,2]
  v = __float_as_int(__int_as_float(v) + __int_as_float(t));
  t = __builtin_amdgcn_update_dpp(0, v, 0x4E, 0xF, 0xF, true);   // quad_perm [2,3,0,1]
  v = __float_as_int(__int_as_float(v) + __int_as_float(t));
  t = __builtin_amdgcn_update_dpp(0, v, 0x141, 0xF, 0xF, true);  // row_half_mirror (^7)
  v = __float_as_int(__int_as_float(v) + __int_as_float(t));
  t = __builtin_amdgcn_update_dpp(0, v, 0x140, 0xF, 0xF, true);  // row_mirror (^15)
  v = __float_as_int(__int_as_float(v) + __int_as_float(t));
  return __int_as_float(v);
}

// ---------------- fused prologue: count_deg | cvt_x | cvt_w | cvt_b | zero gacc ----
#define PREP_CNT 938
#define PREP_CVTX 3750
#define PREP_CVTW 576
#define PREP_CVTB 9
#define PREP_GACC 64
#define B_CVTX (PREP_CNT)
#define B_CVTW (B_CVTX + PREP_CVTX)
#define B_CVTB (B_CVTW + PREP_CVTW)
#define B_GACC (B_CVTB + PREP_CVTB)
#define PREP_BLOCKS (B_GACC + PREP_GACC)

__global__ __launch_bounds__(256) void k_prep(
    const int* __restrict__ dst, int* __restrict__ deg,
    const float* __restrict__ x, unsigned short* __restrict__ xhi,
    unsigned short* __restrict__ xlo,
    const float* __restrict__ Wq, const float* __restrict__ Wk,
    const float* __restrict__ Wv, unsigned short* __restrict__ wthi,
    const float* __restrict__ bq, const float* __restrict__ bk,
    const float* __restrict__ bv, float* __restrict__ bcat,
    float* __restrict__ gacc) {
  __shared__ float tile[32][33];
  int bid = blockIdx.x, t = threadIdx.x;
  if (bid < PREP_CNT) {
    int e = bid * 256 + t;
    if (e < N_EDGES) atomicAdd(&deg[dst[e]], 1);
  } else if (bid < B_CVTW) {
    size_t i0 = ((size_t)(bid - B_CVTX) * 256 + t) * 8;
#pragma unroll
    for (int h = 0; h < 2; ++h) {
      float4 v4 = *(const float4*)(x + i0 + h * 4);
      ushort4 hv, lv;
      hv.x = f2bf(v4.x); lv.x = f2bf(v4.x - bf2f(hv.x));
      hv.y = f2bf(v4.y); lv.y = f2bf(v4.y - bf2f(hv.y));
      hv.z = f2bf(v4.z); lv.z = f2bf(v4.z - bf2f(hv.z));
      hv.w = f2bf(v4.w); lv.w = f2bf(v4.w - bf2f(hv.w));
      *(ushort4*)(xhi + i0 + h * 4) = hv;
      *(ushort4*)(xlo + i0 + h * 4) = lv;
    }
  } else if (bid < B_CVTB) {
    int rel = bid - B_CVTW;
    int k0 = (rel & 7) * 32;
    int n0g = ((rel >> 3) % 24) * 32;
    int l = rel / 192;
    int which = n0g >> 8;
    int col0 = n0g & 255;
    const float* W = (which == 0) ? Wq : ((which == 1) ? Wk : Wv);
    int c = t & 31, r = t >> 5;
#pragma unroll
    for (int rr = 0; rr < 4; ++rr) {
      int kk = r + rr * 8;
      tile[kk][c] = W[(size_t)l * 65536 + (size_t)(k0 + kk) * 256 + col0 + c];
    }
    __syncthreads();
    int kk = t & 31, nn0 = t >> 5;
#pragma unroll
    for (int rr = 0; rr < 4; ++rr) {
      int nn = nn0 + rr * 8;
      wthi[((size_t)l * 768 + n0g + nn) * 256 + k0 + kk] = f2bf(tile[kk][nn]);
    }
  } else if (bid < B_GACC) {
    int idx = (bid - B_CVTB) * 256 + t;
    if (idx < NLAYERS * 768) {
      int n = idx % 768, l = idx / 768;
      int which = n >> 8, col = n & 255;
      const float* b = (which == 0) ? bq : ((which == 1) ? bk : bv);
      bcat[idx] = b[l * 256 + col];
    }
  } else {
    int idx = (bid - B_GACC) * 256 + t;
    gacc[idx] = 0.f;
  }
}

// ---------------- coalesced scan (transposed order) + histogram ----------------
__global__ __launch_bounds__(1024) void k_scan_sort(
    const int* __restrict__ deg, int* __restrict__ rowstart,
    int* __restrict__ cursor, int* __restrict__ bcur_g) {
  const int R = 30;                 // 30*1024 = 30720 >= N_NODES
  __shared__ int hist8[8][256];
  __shared__ int hist[256];
  __shared__ int wpart[2][16];
  int tid = threadIdx.x;
  int lane = tid & 63, wv = tid >> 6;
  int sub = tid >> 7;
  for (int k = tid; k < 8 * 256; k += 1024) ((int*)hist8)[k] = 0;
  __syncthreads();
  int carry = 0;
  for (int j = 0; j < R; ++j) {
    int idx = j * 1024 + tid;       // coalesced: lane-contiguous
    int v = (idx < N_NODES) ? deg[idx] : 0;
    if (idx < N_NODES) {
      int d = v > 255 ? 255 : v;
      atomicAdd(&hist8[sub][d], 1);
    }
    int s = v;                      // wave-inclusive scan
#pragma unroll
    for (int off = 1; off < 64; off <<= 1) {
      int t2 = __shfl_up(s, off);
      if (lane >= off) s += t2;
    }
    if (lane == 63) wpart[j & 1][wv] = s;
    __syncthreads();
    int wbase = 0, total = 0;
#pragma unroll
    for (int k = 0; k < 16; ++k) {
      int w = wpart[j & 1][k];
      total += w;
      if (k < wv) wbase += w;
    }
    if (idx < N_NODES) {
      int p = carry + wbase + (s - v);
      rowstart[idx] = p;
      cursor[idx]   = p;
    }
    carry += total;
  }
  if (tid == 0) rowstart[N_NODES] = carry;
  if (tid < 256) {
    int a = 0;
#pragma unroll
    for (int k = 0; k < 8; ++k) a += hist8[k][tid];
    hist[tid] = a;
  }
  __syncthreads();
  if (tid == 0) {
    int b = 0;                      // descending exclusive bucket scan
    for (int d = 255; d >= 0; --d) { int h = hist[d]; hist[d] = b; b += h; }
  }
  __syncthreads();
  if (tid < 256) bcur_g[tid] = hist[tid];
}

// ---------------- edge scatter + two-level perm placement ----------------
#define SCAT_EB ((N_EDGES + 255) / 256)   // 938
#define SCAT_NB ((N_NODES + 255) / 256)   // 118
__global__ __launch_bounds__(256) void k_scatter(
    const int* __restrict__ src, const int* __restrict__ dst,
    const int* __restrict__ etype, int* __restrict__ cursor,
    int* __restrict__ packed, const int* __restrict__ deg,
    int* __restrict__ bcur_g, int* __restrict__ perm) {
  int bid = blockIdx.x;
  int t = threadIdx.x;
  if (bid < SCAT_EB) {
    int e = bid * 256 + t;
    if (e < N_EDGES) {
      int p = atomicAdd(&cursor[dst[e]], 1);
      packed[p] = src[e] * NETYPES + etype[e];
    }
  } else {
    __shared__ int hist[256], lbase[256], lcur[256];
    hist[t] = 0;
    lcur[t] = 0;
    __syncthreads();
    int i = (bid - SCAT_EB) * 256 + t;
    int d = 0;
    bool valid = (i < N_NODES);
    if (valid) {
      d = deg[i]; if (d > 255) d = 255;
      atomicAdd(&hist[d], 1);
    }
    __syncthreads();
    int h = hist[t];
    if (h > 0) lbase[t] = atomicAdd(&bcur_g[t], h);
    __syncthreads();
    if (valid) {
      int r = atomicAdd(&lcur[d], 1);
      perm[lbase[d] + r] = i;
    }
  }
}

// ---------------- split-bf16 MFMA GEMM, 2-term (Ahi*Bhi + Alo*Bhi) ----------
// v8: depth-2 prefetch on the triple buffer. Order per K-step:
//   vmcnt(4) [tile k certified] -> s_barrier -> STAGE(k+2) -> ds_read+MFMA.
// STAGE(k+2) writes buf (k-1)%3; safe post-barrier (all waves consumed their
// step-(k-1) ds_reads before arriving — lgkmcnt precedes the MFMAs which
// precede the barrier). Pipeline depth 2 (~320+cy cover) at same 48KB/3 blk/CU.
__global__ __launch_bounds__(256, 3) void k_gemm_mfma(
    const unsigned short* __restrict__ Ahi, const unsigned short* __restrict__ Alo,
    const unsigned short* __restrict__ Bhi,
    const float* __restrict__ bcat, float* __restrict__ qbuf,
    unsigned short* __restrict__ kv) {
  __shared__ unsigned short smem[3 * 8192];

  int tid = threadIdx.x;
  int lane = tid & 63, wave = tid >> 6;
  int bx = blockIdx.x;
  int xcd = bx & 7, slot = bx >> 3;
  int rt = xcd + (slot / 6) * 8;
  if (rt >= 469) return;
  int row0 = rt * 64;
  int n0 = (slot % 6) * 128;
  int wm = (wave >> 1) * 32, wn = (wave & 1) * 64;
  int quad = lane >> 4, l16 = lane & 15;
  int lrow = lane >> 2;
  int chSw = (lane & 3) ^ ((lane >> 3) & 3);
  int rdSw = (quad ^ ((l16 >> 1) & 3)) * 8;

  f32x4 acc[2][4];
#pragma unroll
  for (int i = 0; i < 2; ++i)
#pragma unroll
    for (int j = 0; j < 4; ++j) acc[i][j] = (f32x4)(0.f);

  auto STAGE = [&](int k0, int b) {
    unsigned short* s = smem + b * 8192;
    int garA = row0 + wave * 16 + lrow; if (garA >= N_NODES) garA = N_NODES - 1;
    size_t acol = (size_t)garA * 256 + k0 + chSw * 8;
    async_g2l(Ahi + acol, s + wave * 512);
    async_g2l(Alo + acol, s + 2048 + wave * 512);
#pragma unroll
    for (int r = 0; r < 2; ++r) {
      int brow = r * 64 + wave * 16 + lrow;
      size_t boff = (size_t)(n0 + brow) * 256 + k0 + chSw * 8;
      async_g2l(Bhi + boff, s + 4096 + r * 2048 + wave * 512);
    }
  };

  STAGE(0, 0);
  STAGE(32, 1);
#pragma unroll
  for (int k = 0; k < 8; ++k) {
    int cur = k % 3;
    if (k < 7) {
      asm volatile("s_waitcnt vmcnt(4)" ::: "memory");  // tile k landed
    } else {
      asm volatile("s_waitcnt vmcnt(0)" ::: "memory");
    }
    __builtin_amdgcn_s_barrier();   // all waves: tile k resident, tile k-1 reads done
    if (k < 6) STAGE((k + 2) * 32, (k + 2) % 3);

    const unsigned short* sAhi = smem + cur * 8192;
    const unsigned short* sAlo = sAhi + 2048;
    const unsigned short* sB   = sAhi + 4096;
    short8 ah[2], al[2], bh[4];
#pragma unroll
    for (int i = 0; i < 2; ++i) {
      int off = (wm + i * 16 + l16) * 32 + rdSw;
      ah[i] = *(const short8*)(sAhi + off);
      al[i] = *(const short8*)(sAlo + off);
    }
#pragma unroll
    for (int j = 0; j < 4; ++j) {
      int off = (wn + j * 16 + l16) * 32 + rdSw;
      bh[j] = *(const short8*)(sB + off);
    }
#pragma unroll
    for (int i = 0; i < 2; ++i)
#pragma unroll
      for (int j = 0; j < 4; ++j) {
        acc[i][j] = __builtin_amdgcn_mfma_f32_16x16x32_bf16(ah[i], bh[j], acc[i][j], 0, 0, 0);
        acc[i][j] = __builtin_amdgcn_mfma_f32_16x16x32_bf16(al[i], bh[j], acc[i][j], 0, 0, 0);
      }
  }

  float bj[4];
#pragma unroll
  for (int j = 0; j < 4; ++j) bj[j] = bcat[n0 + wn + j * 16 + l16];
  bool isq = (n0 < 256);
  int cb = n0 - 256;
  int isV = cb >> 8;
  int cc0 = (cb & 255) + wn + l16;
#pragma unroll
  for (int i = 0; i < 2; ++i) {
    int rowb = row0 + wm + i * 16 + quad * 4;
#pragma unroll
    for (int r = 0; r < 4; ++r) {
      int grow = rowb + r;
      if (grow < N_NODES) {
        if (isq) {
          float* cp = qbuf + (size_t)grow * 256 + n0 + wn + l16;
#pragma unroll
          for (int j = 0; j < 4; ++j) cp[j * 16] = acc[i][j][r] + bj[j];
        } else {
          unsigned short* rowp = kv + (size_t)grow * 512 + isV * 4;
#pragma unroll
          for (int j = 0; j < 4; ++j) {
            int c = cc0 + j * 16;
            rowp[((c >> 2) << 3) + (c & 3)] = f2bf(acc[i][j][r] + bj[j]);
          }
        }
      }
    }
  }
}

// ---------------- per-dst-node edge attention (degree-sorted via perm) ----------
__global__ __launch_bounds__(256) void k_attn(
    const float* __restrict__ qbuf, const unsigned short* __restrict__ kv,
    const int* __restrict__ rowstart, const int* __restrict__ deg,
    const int* __restrict__ packed,
    const int* __restrict__ perm, const float* __restrict__ Eemb_l,
    unsigned short* __restrict__ xhi, unsigned short* __restrict__ xlo) {
  __shared__ float ete_s[NETYPES * 256];
  int t = threadIdx.x;
#pragma unroll
  for (int i = 0; i < NETYPES; ++i) ete_s[i * 256 + t] = Eemb_l[i * 256 + t];
  __syncthreads();
  int lane = t & 63;
  int n = perm[blockIdx.x * 4 + (t >> 6)];
  float4 q4 = ((const float4*)(qbuf + (size_t)n * 256))[lane];
  int rs = rowstart[n], re = rs + deg[n];
  float l1 = 0.f, ax1 = 0.f, ay1 = 0.f, az1 = 0.f, aw1 = 0.f;
  float l2 = 0.f, ax2 = 0.f, ay2 = 0.f, az2 = 0.f, aw2 = 0.f;
  int i = rs;
  for (; i + 2 <= re; i += 2) {
    int pkA = packed[i], pkB = packed[i + 1];
    ushort8 cA = ((const ushort8*)(kv + (size_t)(pkA >> 3) * 512))[lane];
    ushort8 cB = ((const ushort8*)(kv + (size_t)(pkB >> 3) * 512))[lane];
    float4 eA = ((const float4*)(ete_s + (pkA & 7) * 256))[lane];
    float4 eB = ((const float4*)(ete_s + (pkB & 7) * 256))[lane];
    float pA = (bf2f(cA[0]) + eA.x) * q4.x + (bf2f(cA[1]) + eA.y) * q4.y +
               (bf2f(cA[2]) + eA.z) * q4.z + (bf2f(cA[3]) + eA.w) * q4.w;
    float pB = (bf2f(cB[0]) + eB.x) * q4.x + (bf2f(cB[1]) + eB.y) * q4.y +
               (bf2f(cB[2]) + eB.z) * q4.z + (bf2f(cB[3]) + eB.w) * q4.w;
    pA = dpp_red_add(pA);
    pB = dpp_red_add(pB);
    float e1 = __expf(pA * 0.125f);
    float e2 = __expf(pB * 0.125f);
    l1 += e1; l2 += e2;
    ax1 = fmaf(e1, bf2f(cA[4]) + eA.x, ax1);
    ay1 = fmaf(e1, bf2f(cA[5]) + eA.y, ay1);
    az1 = fmaf(e1, bf2f(cA[6]) + eA.z, az1);
    aw1 = fmaf(e1, bf2f(cA[7]) + eA.w, aw1);
    ax2 = fmaf(e2, bf2f(cB[4]) + eB.x, ax2);
    ay2 = fmaf(e2, bf2f(cB[5]) + eB.y, ay2);
    az2 = fmaf(e2, bf2f(cB[6]) + eB.z, az2);
    aw2 = fmaf(e2, bf2f(cB[7]) + eB.w, aw2);
  }
  if (i < re) {
    int pk = packed[i];
    ushort8 c = ((const ushort8*)(kv + (size_t)(pk >> 3) * 512))[lane];
    float4 e4 = ((const float4*)(ete_s + (pk & 7) * 256))[lane];
    float p = (bf2f(c[0]) + e4.x) * q4.x + (bf2f(c[1]) + e4.y) * q4.y +
              (bf2f(c[2]) + e4.z) * q4.z + (bf2f(c[3]) + e4.w) * q4.w;
    p = dpp_red_add(p);
    float e1 = __expf(p * 0.125f);
    l1 += e1;
    ax1 = fmaf(e1, bf2f(c[4]) + e4.x, ax1);
    ay1 = fmaf(e1, bf2f(c[5]) + e4.y, ay1);
    az1 = fmaf(e1, bf2f(c[6]) + e4.z, az1);
    aw1 = fmaf(e1, bf2f(c[7]) + e4.w, aw1);
  }
  float l = l1 + l2;
  float inv = 1.f / (l + 1e-16f);
  float4 o;
  o.x = (ax1 + ax2) * inv; o.y = (ay1 + ay2) * inv;
  o.z = (az1 + az2) * inv; o.w = (aw1 + aw2) * inv;
  o.x = o.x > 0.f ? o.x : expm1f(o.x);
  o.y = o.y > 0.f ? o.y : expm1f(o.y);
  o.z = o.z > 0.f ? o.z : expm1f(o.z);
  o.w = o.w > 0.f ? o.w : expm1f(o.w);
  unsigned short h0 = f2bf(o.x), h1 = f2bf(o.y), h2 = f2bf(o.z), h3 = f2bf(o.w);
  ushort4 hv, lv;
  hv.x = h0; hv.y = h1; hv.z = h2; hv.w = h3;
  lv.x = f2bf(o.x - bf2f(h0)); lv.y = f2bf(o.y - bf2f(h1));
  lv.z = f2bf(o.z - bf2f(h2)); lv.w = f2bf(o.w - bf2f(h3));
  size_t base_o = (size_t)n * 256 + lane * 4;
  *(ushort4*)(xhi + base_o) = hv;
  *(ushort4*)(xlo + base_o) = lv;
}

// ---------------- parallel mean pool, stage 1 ----------------
#define POOL_NPB 16
#define POOL_BLOCKS ((N_NODES + POOL_NPB - 1) / POOL_NPB)
__global__ __launch_bounds__(256) void k_pool_partial(
    const unsigned short* __restrict__ xhi, const unsigned short* __restrict__ xlo,
    const int* __restrict__ batch, float* __restrict__ gacc) {
  int t = threadIdx.x;
  int base = blockIdx.x * POOL_NPB;
  int end = base + POOL_NPB; if (end > N_NODES) end = N_NODES;
  __shared__ int bsh[POOL_NPB];
  if (t < POOL_NPB && base + t < N_NODES) bsh[t] = batch[base + t];
  __syncthreads();
  float acc = 0.f;
  int cur = bsh[0];
  for (int n = base; n < end; ++n) {
    int g = bsh[n - base];
    if (g != cur) {
      atomicAdd(&gacc[cur * 256 + t], acc);
      acc = 0.f; cur = g;
    }
    size_t idx = (size_t)n * 256 + t;
    acc += bf2f(xhi[idx]) + bf2f(xlo[idx]);
  }
  atomicAdd(&gacc[cur * 256 + t], acc);
}

// ---------------- GRU (h0=0) + FC ----------------
__device__ inline int lower_bound_dev(const int* a, int n, int val) {
  int lo = 0, hi = n;
  while (lo < hi) {
    int mid = (lo + hi) >> 1;
    if (a[mid] < val) lo = mid + 1; else hi = mid;
  }
  return lo;
}

__global__ __launch_bounds__(256) void k_gru_fc(
    const float* __restrict__ gacc, const int* __restrict__ batch,
    const float* __restrict__ W_ih, const float* __restrict__ b_ih,
    const float* __restrict__ b_hh, const float* __restrict__ W_fc,
    const float* __restrict__ b_fc, float* __restrict__ out) {
  __shared__ float gv[256];
  __shared__ float gates[192];
  __shared__ float h[64];
  int gr = blockIdx.x, t = threadIdx.x;
  int s0 = lower_bound_dev(batch, N_NODES, gr);
  int e0 = lower_bound_dev(batch, N_NODES, gr + 1);
  float c = (e0 > s0) ? (float)(e0 - s0) : 1.f;
  gv[t] = gacc[gr * 256 + t] / c;
  __syncthreads();
  if (t < 192) {
    const float* wr = W_ih + t * 256;
    float s = b_ih[t];
    for (int k = 0; k < 256; ++k) s = fmaf(gv[k], wr[k], s);
    gates[t] = s;
  }
  __syncthreads();
  if (t < 64) {
    float r  = 1.f / (1.f + expf(-(gates[t] + b_hh[t])));
    float z  = 1.f / (1.f + expf(-(gates[64 + t] + b_hh[64 + t])));
    float nn = tanhf(gates[128 + t] + r * b_hh[128 + t]);
    h[t] = (1.f - z) * nn;
  }
  __syncthreads();
  if (t < 2) {
    const float* wr = W_fc + t * 64;
    float s = b_fc[t];
    for (int k = 0; k < 64; ++k) s = fmaf(h[k], wr[k], s);
    out[gr * 2 + t] = s;
  }
}

extern "C" void kernel_launch(void* const* d_in, const int* in_sizes, int n_in,
                              void* d_out, int out_size, void* d_ws, size_t ws_size,
                              hipStream_t stream) {
  const float* x     = (const float*)d_in[0];
  const int* edge_index = (const int*)d_in[1];
  const int* batch   = (const int*)d_in[2];
  const int* etype   = (const int*)d_in[3];
  const float* Wq    = (const float*)d_in[4];
  const float* bq    = (const float*)d_in[5];
  const float* Wk    = (const float*)d_in[6];
  const float* bk    = (const float*)d_in[7];
  const float* Wv    = (const float*)d_in[8];
  const float* bv    = (const float*)d_in[9];
  const float* Eemb  = (const float*)d_in[10];
  const float* W_ih  = (const float*)d_in[11];
  const float* b_ih  = (const float*)d_in[12];
  const float* b_hh  = (const float*)d_in[14];
  const float* W_fc  = (const float*)d_in[15];
  const float* b_fc  = (const float*)d_in[16];
  float* out = (float*)d_out;

  const int* src = edge_index;
  const int* dst = edge_index + N_EDGES;

  float* qbuf  = (float*)d_ws;                             // N*256 f32
  float* gacc  = qbuf + (size_t)N_NODES * 256;             // 64*256
  float* bcat  = gacc + NGRAPHS * 256;                     // 3*768
  unsigned short* kv   = (unsigned short*)(bcat + NLAYERS * 768);  // N*512 bf16
  unsigned short* xhi  = kv + (size_t)N_NODES * 512;       // N*256
  unsigned short* xlo  = xhi + (size_t)N_NODES * 256;
  unsigned short* wthi = xlo + (size_t)N_NODES * 256;      // 3*768*256
  int* deg      = (int*)(wthi + (size_t)NLAYERS * 768 * 256);
  int* rowstart = deg + N_NODES;
  int* cursor   = rowstart + N_NODES + 1;
  int* packed   = cursor + N_NODES;
  int* perm     = packed + N_EDGES;
  int* bcur_g   = perm + N_NODES;

  hipMemsetAsync(deg, 0, N_NODES * sizeof(int), stream);
  k_prep<<<PREP_BLOCKS, 256, 0, stream>>>(dst, deg, x, xhi, xlo,
                                          Wq, Wk, Wv, wthi, bq, bk, bv, bcat, gacc);
  k_scan_sort<<<1, 1024, 0, stream>>>(deg, rowstart, cursor, bcur_g);
  k_scatter<<<SCAT_EB + SCAT_NB, 256, 0, stream>>>(src, dst, etype, cursor, packed,
                                                   deg, bcur_g, perm);

  for (int l = 0; l < NLAYERS; ++l) {
    k_gemm_mfma<<<59 * 8 * 6, 256, 0, stream>>>(
        xhi, xlo, wthi + (size_t)l * 768 * 256,
        bcat + l * 768, qbuf, kv);
    k_attn<<<N_NODES / 4, 256, 0, stream>>>(qbuf, kv, rowstart, deg, packed, perm,
                                            Eemb + (size_t)l * NETYPES * 256, xhi, xlo);
  }
  k_pool_partial<<<POOL_BLOCKS, 256, 0, stream>>>(xhi, xlo, batch, gacc);
  k_gru_fc<<<NGRAPHS, 256, 0, stream>>>(gacc, batch, W_ih, b_ih, b_hh, W_fc, b_fc, out);
}